// Round 1
// baseline (3748.198 us; speedup 1.0000x reference)
//
#include <hip/hip_runtime.h>
#include <hip/hip_bf16.h>
#include <stdint.h>

typedef __bf16 bf16_t;
typedef __bf16 bf16x8 __attribute__((ext_vector_type(8)));
typedef __bf16 bf16x4 __attribute__((ext_vector_type(4)));
typedef float f32x4 __attribute__((ext_vector_type(4)));

constexpr int SEQ = 4096;
constexpr int DIM = 1024;
constexpr int KEY = 1024;
constexpr int MLP = 4096;
constexpr int VOC = 32000;
constexpr int NLAYER = 8;

__device__ __forceinline__ void gld_lds16(const bf16_t* g, bf16_t* lds) {
  __builtin_amdgcn_global_load_lds(
      (__attribute__((address_space(1))) void*)g,
      (__attribute__((address_space(3))) void*)lds,
      16, 0, 0);
}

// C[i,j] = sum_d A[i,d] * B[j,d]  (+ bias[j])
// A: [M=4096][Kd] bf16 row-major (lda), B: [N][Kd] bf16 row-major (ldb)
// MODE 0: fp32 store; 1: bf16 store; 2: bf16 relu store; 3: fp32 +=
template <int MODE>
__global__ __launch_bounds__(256) void gemm_nt(
    const bf16_t* __restrict__ A, int lda,
    const bf16_t* __restrict__ B, int ldb,
    void* __restrict__ Cp, int ldc,
    const float* __restrict__ bias,
    int Kd) {
  __shared__ __attribute__((aligned(16))) bf16_t As[128 * 32];
  __shared__ __attribute__((aligned(16))) bf16_t Bs[128 * 32];
  const int t = threadIdx.x;
  const int l = t & 63;
  const int w = t >> 6;
  const int brow = blockIdx.y * 128;
  const int bcol = blockIdx.x * 128;
  const int wr = (w >> 1) * 64;
  const int wc = (w & 1) * 64;

  f32x4 acc[4][4] = {};

  const int srow = t >> 2;          // 0..63
  const int scol = (t & 3) * 8;     // 0,8,16,24
  const bf16_t* Ag = A + (size_t)(brow + srow) * lda + scol;
  const bf16_t* Bg = B + (size_t)(bcol + srow) * ldb + scol;
  bf16_t* AsD = &As[t * 8];
  bf16_t* BsD = &Bs[t * 8];

  const int arow = wr + (l & 15);
  const int brw = wc + (l & 15);
  const int kq = (l >> 4) * 8;

  for (int kt = 0; kt < Kd; kt += 32) {
    if (kt) __syncthreads();
    gld_lds16(Ag + kt, AsD);
    gld_lds16(Ag + kt + (size_t)64 * lda, AsD + 2048);
    gld_lds16(Bg + kt, BsD);
    gld_lds16(Bg + kt + (size_t)64 * ldb, BsD + 2048);
    __syncthreads();
    bf16x8 af[4], bfr[4];
#pragma unroll
    for (int mi = 0; mi < 4; ++mi)
      af[mi] = *(const bf16x8*)&As[(arow + mi * 16) * 32 + kq];
#pragma unroll
    for (int ni = 0; ni < 4; ++ni)
      bfr[ni] = *(const bf16x8*)&Bs[(brw + ni * 16) * 32 + kq];
#pragma unroll
    for (int mi = 0; mi < 4; ++mi)
#pragma unroll
      for (int ni = 0; ni < 4; ++ni)
        acc[mi][ni] = __builtin_amdgcn_mfma_f32_16x16x32_bf16(
            af[mi], bfr[ni], acc[mi][ni], 0, 0, 0);
  }

  const int crow0 = brow + wr + (l >> 4) * 4;
  const int ccol0 = bcol + wc + (l & 15);
#pragma unroll
  for (int mi = 0; mi < 4; ++mi) {
#pragma unroll
    for (int ni = 0; ni < 4; ++ni) {
      const int col = ccol0 + ni * 16;
      const float bv = bias ? bias[col] : 0.0f;
#pragma unroll
      for (int r = 0; r < 4; ++r) {
        const int row = crow0 + mi * 16 + r;
        const float v = acc[mi][ni][r] + bv;
        const size_t idx = (size_t)row * ldc + col;
        if (MODE == 0)
          ((float*)Cp)[idx] = v;
        else if (MODE == 1)
          ((bf16_t*)Cp)[idx] = (bf16_t)v;
        else if (MODE == 2)
          ((bf16_t*)Cp)[idx] = (bf16_t)fmaxf(v, 0.0f);
        else
          ((float*)Cp)[idx] += v;
      }
    }
  }
}

// row-wise softmax over 4096 fp32 -> bf16
__global__ __launch_bounds__(256) void softmax_kernel(
    const float* __restrict__ S, bf16_t* __restrict__ P) {
  const int row = blockIdx.x;
  const int t = threadIdx.x;
  const float4* s4 = (const float4*)(S + (size_t)row * SEQ);
  float4 v[4];
  float mx = -3.0e38f;
#pragma unroll
  for (int j = 0; j < 4; ++j) {
    v[j] = s4[j * 256 + t];
    mx = fmaxf(mx, fmaxf(fmaxf(v[j].x, v[j].y), fmaxf(v[j].z, v[j].w)));
  }
#pragma unroll
  for (int off = 32; off >= 1; off >>= 1) mx = fmaxf(mx, __shfl_xor(mx, off));
  __shared__ float redm[4];
  __shared__ float reds[4];
  if ((t & 63) == 0) redm[t >> 6] = mx;
  __syncthreads();
  mx = fmaxf(fmaxf(redm[0], redm[1]), fmaxf(redm[2], redm[3]));
  float e[16];
  float sum = 0.0f;
#pragma unroll
  for (int j = 0; j < 4; ++j) {
    e[4 * j + 0] = __expf(v[j].x - mx);
    e[4 * j + 1] = __expf(v[j].y - mx);
    e[4 * j + 2] = __expf(v[j].z - mx);
    e[4 * j + 3] = __expf(v[j].w - mx);
    sum += e[4 * j + 0] + e[4 * j + 1] + e[4 * j + 2] + e[4 * j + 3];
  }
#pragma unroll
  for (int off = 32; off >= 1; off >>= 1) sum += __shfl_xor(sum, off);
  if ((t & 63) == 0) reds[t >> 6] = sum;
  __syncthreads();
  sum = reds[0] + reds[1] + reds[2] + reds[3];
  const float inv = 1.0f / sum;
  bf16x4* p4 = (bf16x4*)(P + (size_t)row * SEQ);
#pragma unroll
  for (int j = 0; j < 4; ++j) {
    bf16x4 o;
    o[0] = (bf16_t)(e[4 * j + 0] * inv);
    o[1] = (bf16_t)(e[4 * j + 1] * inv);
    o[2] = (bf16_t)(e[4 * j + 2] * inv);
    o[3] = (bf16_t)(e[4 * j + 3] * inv);
    p4[j * 256 + t] = o;
  }
}

// fp32 [R][C] -> bf16 [C][R] (transpose + convert)
__global__ void cvtT_kernel(const float* __restrict__ in,
                            bf16_t* __restrict__ out, int R, int C) {
  __shared__ float tile[32][33];
  const int c0 = blockIdx.x * 32, r0 = blockIdx.y * 32;
  const int x = threadIdx.x, y = threadIdx.y;
#pragma unroll
  for (int k = 0; k < 4; ++k)
    tile[y + 8 * k][x] = in[(size_t)(r0 + y + 8 * k) * C + c0 + x];
  __syncthreads();
#pragma unroll
  for (int k = 0; k < 4; ++k)
    out[(size_t)(c0 + y + 8 * k) * R + r0 + x] = (bf16_t)tile[x][y + 8 * k];
}

// bf16 [R][C] -> bf16 [C][R]
__global__ void transT_bf16(const bf16_t* __restrict__ in,
                            bf16_t* __restrict__ out, int R, int C) {
  __shared__ bf16_t tile[32][33];
  const int c0 = blockIdx.x * 32, r0 = blockIdx.y * 32;
  const int x = threadIdx.x, y = threadIdx.y;
#pragma unroll
  for (int k = 0; k < 4; ++k)
    tile[y + 8 * k][x] = in[(size_t)(r0 + y + 8 * k) * C + c0 + x];
  __syncthreads();
#pragma unroll
  for (int k = 0; k < 4; ++k)
    out[(size_t)(c0 + y + 8 * k) * R + r0 + x] = tile[x][y + 8 * k];
}

__global__ void cvt_f32_bf16(const float* __restrict__ in,
                             bf16_t* __restrict__ out, int n4) {
  int i = blockIdx.x * 256 + threadIdx.x;
  const int stride = gridDim.x * 256;
  for (; i < n4; i += stride) {
    const float4 f = ((const float4*)in)[i];
    bf16x4 o;
    o[0] = (bf16_t)f.x;
    o[1] = (bf16_t)f.y;
    o[2] = (bf16_t)f.z;
    o[3] = (bf16_t)f.w;
    ((bf16x4*)out)[i] = o;
  }
}

__global__ __launch_bounds__(256) void embed_kernel(
    const int* __restrict__ x, const float* __restrict__ tok,
    const float* __restrict__ pos, float* __restrict__ h) {
  const int n = blockIdx.x, t = threadIdx.x;
  const int id = x[n];
  const float4 a = ((const float4*)(tok + (size_t)id * DIM))[t];
  const float4 b = ((const float4*)(pos + (size_t)n * DIM))[t];
  float4 o;
  o.x = a.x + b.x;
  o.y = a.y + b.y;
  o.z = a.z + b.z;
  o.w = a.w + b.w;
  ((float4*)(h + (size_t)n * DIM))[t] = o;
}

// out[n,v] = v < DIM ? h[n,v] : 0   (unembed is eye(D,V))
__global__ __launch_bounds__(256) void output_kernel(
    const float* __restrict__ h, float* __restrict__ out) {
  const int n = blockIdx.y;
  const int i4 = blockIdx.x * 256 + threadIdx.x;
  if (i4 >= VOC / 4) return;
  float4 v = make_float4(0.0f, 0.0f, 0.0f, 0.0f);
  if (i4 < DIM / 4) v = ((const float4*)(h + (size_t)n * DIM))[i4];
  ((float4*)(out + (size_t)n * VOC))[i4] = v;
}

extern "C" void kernel_launch(void* const* d_in, const int* in_sizes, int n_in,
                              void* d_out, int out_size, void* d_ws,
                              size_t ws_size, hipStream_t stream) {
  const int* x = (const int*)d_in[0];
  const float* tok = (const float*)d_in[1];
  const float* pos = (const float*)d_in[2];
  const float* Wq = (const float*)d_in[3];
  const float* bq = (const float*)d_in[4];
  const float* Wk = (const float*)d_in[5];
  const float* bk = (const float*)d_in[6];
  const float* Wv = (const float*)d_in[7];
  const float* bv = (const float*)d_in[8];
  const float* Wo = (const float*)d_in[9];
  const float* bo = (const float*)d_in[10];
  const float* W1 = (const float*)d_in[11];
  const float* b1 = (const float*)d_in[12];
  const float* W2 = (const float*)d_in[13];
  const float* b2 = (const float*)d_in[14];
  float* out = (float*)d_out;

  char* ws = (char*)d_ws;
  constexpr size_t MB = 1ull << 20;
  // ws layout (184 MB total)
  float* h = (float*)(ws + 0);             // 16MB fp32 residual stream
  bf16_t* hb = (bf16_t*)(ws + 16 * MB);    // 8MB
  bf16_t* qb = (bf16_t*)(ws + 24 * MB);    // 8MB
  bf16_t* kb = (bf16_t*)(ws + 32 * MB);    // 8MB
  bf16_t* vb = (bf16_t*)(ws + 40 * MB);    // 8MB
  bf16_t* vT = (bf16_t*)(ws + 48 * MB);    // 8MB
  bf16_t* Ob = (bf16_t*)(ws + 56 * MB);    // 8MB
  float* S = (float*)(ws + 64 * MB);       // 64MB
  bf16_t* mh = (bf16_t*)(ws + 64 * MB);    // 32MB (aliases S; disjoint in time)
  bf16_t* P = (bf16_t*)(ws + 128 * MB);    // 32MB
  bf16_t* WqT = (bf16_t*)(ws + 160 * MB);  // 2MB each
  bf16_t* WkT = (bf16_t*)(ws + 162 * MB);
  bf16_t* WvT = (bf16_t*)(ws + 164 * MB);
  bf16_t* WoT = (bf16_t*)(ws + 166 * MB);
  bf16_t* W1T = (bf16_t*)(ws + 168 * MB);  // 8MB
  bf16_t* W2T = (bf16_t*)(ws + 176 * MB);  // 8MB

  embed_kernel<<<SEQ, 256, 0, stream>>>(x, tok, pos, h);

  const dim3 tb(32, 8);
  for (int l = 0; l < NLAYER; ++l) {
    const float* lWq = Wq + (size_t)l * DIM * KEY;
    const float* lWk = Wk + (size_t)l * DIM * KEY;
    const float* lWv = Wv + (size_t)l * DIM * KEY;
    const float* lWo = Wo + (size_t)l * KEY * DIM;
    const float* lW1 = W1 + (size_t)l * DIM * MLP;
    const float* lW2 = W2 + (size_t)l * MLP * DIM;

    cvtT_kernel<<<dim3(KEY / 32, DIM / 32), tb, 0, stream>>>(lWq, WqT, DIM, KEY);
    cvtT_kernel<<<dim3(KEY / 32, DIM / 32), tb, 0, stream>>>(lWk, WkT, DIM, KEY);
    cvtT_kernel<<<dim3(KEY / 32, DIM / 32), tb, 0, stream>>>(lWv, WvT, DIM, KEY);
    cvtT_kernel<<<dim3(DIM / 32, KEY / 32), tb, 0, stream>>>(lWo, WoT, KEY, DIM);
    cvtT_kernel<<<dim3(MLP / 32, DIM / 32), tb, 0, stream>>>(lW1, W1T, DIM, MLP);
    cvtT_kernel<<<dim3(DIM / 32, MLP / 32), tb, 0, stream>>>(lW2, W2T, MLP, DIM);

    cvt_f32_bf16<<<1024, 256, 0, stream>>>(h, hb, SEQ * DIM / 4);

    const dim3 g_qkv(KEY / 128, SEQ / 128);
    gemm_nt<1><<<g_qkv, 256, 0, stream>>>(hb, DIM, WqT, DIM, qb, KEY, bq + (size_t)l * KEY, DIM);
    gemm_nt<1><<<g_qkv, 256, 0, stream>>>(hb, DIM, WkT, DIM, kb, KEY, bk + (size_t)l * KEY, DIM);
    gemm_nt<1><<<g_qkv, 256, 0, stream>>>(hb, DIM, WvT, DIM, vb, KEY, bv + (size_t)l * KEY, DIM);

    transT_bf16<<<dim3(KEY / 32, SEQ / 32), tb, 0, stream>>>(vb, vT, SEQ, KEY);

    // S = Q K^T  [4096 x 4096] fp32
    gemm_nt<0><<<dim3(SEQ / 128, SEQ / 128), 256, 0, stream>>>(qb, KEY, kb, KEY, S, SEQ, nullptr, KEY);

    softmax_kernel<<<SEQ, 256, 0, stream>>>(S, P);

    // O = P V   (B = V^T [KEY][SEQ])
    gemm_nt<1><<<dim3(KEY / 128, SEQ / 128), 256, 0, stream>>>(P, SEQ, vT, SEQ, Ob, KEY, nullptr, SEQ);

    // h += O Wo + bo
    gemm_nt<3><<<dim3(DIM / 128, SEQ / 128), 256, 0, stream>>>(Ob, KEY, WoT, KEY, h, DIM, bo + (size_t)l * DIM, KEY);

    cvt_f32_bf16<<<1024, 256, 0, stream>>>(h, hb, SEQ * DIM / 4);

    // mh = relu(h W1 + b1)
    gemm_nt<2><<<dim3(MLP / 128, SEQ / 128), 256, 0, stream>>>(hb, DIM, W1T, DIM, mh, MLP, b1 + (size_t)l * MLP, DIM);

    // h += mh W2 + b2
    gemm_nt<3><<<dim3(DIM / 128, SEQ / 128), 256, 0, stream>>>(mh, MLP, W2T, MLP, h, DIM, b2 + (size_t)l * DIM, MLP);
  }

  output_kernel<<<dim3((VOC / 4 + 255) / 256, SEQ), 256, 0, stream>>>(h, out);
}

// Round 2
// 3043.988 us; speedup vs baseline: 1.2313x; 1.2313x over previous
//
#include <hip/hip_runtime.h>
#include <hip/hip_bf16.h>
#include <stdint.h>

typedef __bf16 bf16_t;
typedef __bf16 bf16x8 __attribute__((ext_vector_type(8)));
typedef __bf16 bf16x4 __attribute__((ext_vector_type(4)));
typedef float f32x4 __attribute__((ext_vector_type(4)));

constexpr int SEQ = 4096;
constexpr int DIM = 1024;
constexpr int KEY = 1024;
constexpr int MLP = 4096;
constexpr int VOC = 32000;
constexpr int NLAYER = 8;

__device__ __forceinline__ void gld_lds16(const bf16_t* g, bf16_t* lds) {
  __builtin_amdgcn_global_load_lds(
      (__attribute__((address_space(1))) void*)g,
      (__attribute__((address_space(3))) void*)lds,
      16, 0, 0);
}

// C[i,j] = sum_d A[i,d] * B[j,d]  (+ bias[j])
// A: [M][Kd] bf16 (lda), B: [N][Kd] bf16 (ldb). Block tile 128 x BN.
// MODE 0: fp32 store; 1: bf16 store; 2: bf16 relu store;
// MODE 4: fp32 Cp[idx] += v, and Cb[idx] = bf16(new value)
template <int MODE, int BN>
__global__ __launch_bounds__(256) void gemm_nt(
    const bf16_t* __restrict__ A, int lda,
    const bf16_t* __restrict__ B, int ldb,
    void* __restrict__ Cp, int ldc,
    const float* __restrict__ bias,
    int Kd, bf16_t* __restrict__ Cb) {
  __shared__ __attribute__((aligned(16))) bf16_t As[128 * 32];
  __shared__ __attribute__((aligned(16))) bf16_t Bs[BN * 32];
  const int t = threadIdx.x;
  const int l = t & 63;
  const int w = t >> 6;
  const int brow = blockIdx.y * 128;
  const int bcol = blockIdx.x * BN;
  const int wr = (w >> 1) * 64;
  const int wc = (w & 1) * (BN / 2);
  constexpr int NF = BN / 32;  // 4 (BN=128) or 2 (BN=64)

  f32x4 acc[4][NF] = {};

  const int srow = t >> 2;       // 0..63
  const int scol = (t & 3) * 8;  // 0,8,16,24
  const bf16_t* Ag = A + (size_t)(brow + srow) * lda + scol;
  const bf16_t* Bg = B + (size_t)(bcol + srow) * ldb + scol;
  bf16_t* AsD = &As[t * 8];
  bf16_t* BsD = &Bs[t * 8];

  const int arow = wr + (l & 15);
  const int brw = wc + (l & 15);
  const int kq = (l >> 4) * 8;

  for (int kt = 0; kt < Kd; kt += 32) {
    if (kt) __syncthreads();
    gld_lds16(Ag + kt, AsD);
    gld_lds16(Ag + kt + (size_t)64 * lda, AsD + 2048);
    gld_lds16(Bg + kt, BsD);
    if (BN == 128) gld_lds16(Bg + kt + (size_t)64 * ldb, BsD + 2048);
    __syncthreads();
    bf16x8 af[4], bfr[NF];
#pragma unroll
    for (int mi = 0; mi < 4; ++mi)
      af[mi] = *(const bf16x8*)&As[(arow + mi * 16) * 32 + kq];
#pragma unroll
    for (int ni = 0; ni < NF; ++ni)
      bfr[ni] = *(const bf16x8*)&Bs[(brw + ni * 16) * 32 + kq];
#pragma unroll
    for (int mi = 0; mi < 4; ++mi)
#pragma unroll
      for (int ni = 0; ni < NF; ++ni)
        acc[mi][ni] = __builtin_amdgcn_mfma_f32_16x16x32_bf16(
            af[mi], bfr[ni], acc[mi][ni], 0, 0, 0);
  }

  const int crow0 = brow + wr + (l >> 4) * 4;
  const int ccol0 = bcol + wc + (l & 15);
#pragma unroll
  for (int mi = 0; mi < 4; ++mi) {
#pragma unroll
    for (int ni = 0; ni < NF; ++ni) {
      const int col = ccol0 + ni * 16;
      const float bv = bias ? bias[col] : 0.0f;
#pragma unroll
      for (int r = 0; r < 4; ++r) {
        const int row = crow0 + mi * 16 + r;
        const float v = acc[mi][ni][r] + bv;
        const size_t idx = (size_t)row * ldc + col;
        if (MODE == 0) {
          ((float*)Cp)[idx] = v;
        } else if (MODE == 1) {
          ((bf16_t*)Cp)[idx] = (bf16_t)v;
        } else if (MODE == 2) {
          ((bf16_t*)Cp)[idx] = (bf16_t)fmaxf(v, 0.0f);
        } else {
          const float nv = ((float*)Cp)[idx] + v;
          ((float*)Cp)[idx] = nv;
          Cb[idx] = (bf16_t)nv;
        }
      }
    }
  }
}

// row-wise softmax over 4096 fp32 -> bf16
__global__ __launch_bounds__(256) void softmax_kernel(
    const float* __restrict__ S, bf16_t* __restrict__ P) {
  const int row = blockIdx.x;
  const int t = threadIdx.x;
  const float4* s4 = (const float4*)(S + (size_t)row * SEQ);
  float4 v[4];
  float mx = -3.0e38f;
#pragma unroll
  for (int j = 0; j < 4; ++j) {
    v[j] = s4[j * 256 + t];
    mx = fmaxf(mx, fmaxf(fmaxf(v[j].x, v[j].y), fmaxf(v[j].z, v[j].w)));
  }
#pragma unroll
  for (int off = 32; off >= 1; off >>= 1) mx = fmaxf(mx, __shfl_xor(mx, off));
  __shared__ float redm[4];
  __shared__ float reds[4];
  if ((t & 63) == 0) redm[t >> 6] = mx;
  __syncthreads();
  mx = fmaxf(fmaxf(redm[0], redm[1]), fmaxf(redm[2], redm[3]));
  float e[16];
  float sum = 0.0f;
#pragma unroll
  for (int j = 0; j < 4; ++j) {
    e[4 * j + 0] = __expf(v[j].x - mx);
    e[4 * j + 1] = __expf(v[j].y - mx);
    e[4 * j + 2] = __expf(v[j].z - mx);
    e[4 * j + 3] = __expf(v[j].w - mx);
    sum += e[4 * j + 0] + e[4 * j + 1] + e[4 * j + 2] + e[4 * j + 3];
  }
#pragma unroll
  for (int off = 32; off >= 1; off >>= 1) sum += __shfl_xor(sum, off);
  if ((t & 63) == 0) reds[t >> 6] = sum;
  __syncthreads();
  sum = reds[0] + reds[1] + reds[2] + reds[3];
  const float inv = 1.0f / sum;
  bf16x4* p4 = (bf16x4*)(P + (size_t)row * SEQ);
#pragma unroll
  for (int j = 0; j < 4; ++j) {
    bf16x4 o;
    o[0] = (bf16_t)(e[4 * j + 0] * inv);
    o[1] = (bf16_t)(e[4 * j + 1] * inv);
    o[2] = (bf16_t)(e[4 * j + 2] * inv);
    o[3] = (bf16_t)(e[4 * j + 3] * inv);
    p4[j * 256 + t] = o;
  }
}

// fp32 [R][C] -> bf16 [C][R] (transpose + convert), out row offset
__global__ void cvtT_kernel(const float* __restrict__ in,
                            bf16_t* __restrict__ out, int R, int C) {
  __shared__ float tile[32][33];
  const int c0 = blockIdx.x * 32, r0 = blockIdx.y * 32;
  const int x = threadIdx.x, y = threadIdx.y;
#pragma unroll
  for (int k = 0; k < 4; ++k)
    tile[y + 8 * k][x] = in[(size_t)(r0 + y + 8 * k) * C + c0 + x];
  __syncthreads();
#pragma unroll
  for (int k = 0; k < 4; ++k)
    out[(size_t)(c0 + y + 8 * k) * R + r0 + x] = (bf16_t)tile[x][y + 8 * k];
}

// batched: z selects Wq/Wk/Wv [D][K]; out rows z*K + [0,K)
__global__ void cvtT_qkv(const float* __restrict__ Wq,
                         const float* __restrict__ Wk,
                         const float* __restrict__ Wv,
                         bf16_t* __restrict__ out) {
  __shared__ float tile[32][33];
  const int z = blockIdx.z;
  const float* in = (z == 0) ? Wq : (z == 1) ? Wk : Wv;
  bf16_t* o = out + (size_t)z * KEY * DIM;
  const int c0 = blockIdx.x * 32, r0 = blockIdx.y * 32;
  const int x = threadIdx.x, y = threadIdx.y;
#pragma unroll
  for (int k = 0; k < 4; ++k)
    tile[y + 8 * k][x] = in[(size_t)(r0 + y + 8 * k) * KEY + c0 + x];
  __syncthreads();
#pragma unroll
  for (int k = 0; k < 4; ++k)
    o[(size_t)(c0 + y + 8 * k) * DIM + r0 + x] = (bf16_t)tile[x][y + 8 * k];
}

__global__ void bias_cat3(const float* __restrict__ a,
                          const float* __restrict__ b,
                          const float* __restrict__ c,
                          float* __restrict__ out) {
  const int i = blockIdx.x * 256 + threadIdx.x;
  if (i < KEY)
    out[i] = a[i];
  else if (i < 2 * KEY)
    out[i] = b[i - KEY];
  else if (i < 3 * KEY)
    out[i] = c[i - 2 * KEY];
}

// bf16 [R][C] (ldin) -> bf16 [C][R]
__global__ void transT_bf16(const bf16_t* __restrict__ in, int ldin,
                            bf16_t* __restrict__ out, int R, int C) {
  __shared__ bf16_t tile[32][33];
  const int c0 = blockIdx.x * 32, r0 = blockIdx.y * 32;
  const int x = threadIdx.x, y = threadIdx.y;
#pragma unroll
  for (int k = 0; k < 4; ++k)
    tile[y + 8 * k][x] = in[(size_t)(r0 + y + 8 * k) * ldin + c0 + x];
  __syncthreads();
#pragma unroll
  for (int k = 0; k < 4; ++k)
    out[(size_t)(c0 + y + 8 * k) * R + r0 + x] = tile[x][y + 8 * k];
}

__global__ __launch_bounds__(256) void embed_kernel(
    const int* __restrict__ x, const float* __restrict__ tok,
    const float* __restrict__ pos, float* __restrict__ h,
    bf16_t* __restrict__ hb) {
  const int n = blockIdx.x, t = threadIdx.x;
  const int id = x[n];
  const float4 a = ((const float4*)(tok + (size_t)id * DIM))[t];
  const float4 b = ((const float4*)(pos + (size_t)n * DIM))[t];
  float4 o;
  o.x = a.x + b.x;
  o.y = a.y + b.y;
  o.z = a.z + b.z;
  o.w = a.w + b.w;
  ((float4*)(h + (size_t)n * DIM))[t] = o;
  bf16x4 ob;
  ob[0] = (bf16_t)o.x;
  ob[1] = (bf16_t)o.y;
  ob[2] = (bf16_t)o.z;
  ob[3] = (bf16_t)o.w;
  ((bf16x4*)(hb + (size_t)n * DIM))[t] = ob;
}

// out[n,v] = v < DIM ? h[n,v] : 0   (unembed is eye(D,V))
__global__ __launch_bounds__(256) void output_kernel(
    const float* __restrict__ h, float* __restrict__ out) {
  const int n = blockIdx.y;
  const int i4 = blockIdx.x * 256 + threadIdx.x;
  if (i4 >= VOC / 4) return;
  float4 v = make_float4(0.0f, 0.0f, 0.0f, 0.0f);
  if (i4 < DIM / 4) v = ((const float4*)(h + (size_t)n * DIM))[i4];
  ((float4*)(out + (size_t)n * VOC))[i4] = v;
}

extern "C" void kernel_launch(void* const* d_in, const int* in_sizes, int n_in,
                              void* d_out, int out_size, void* d_ws,
                              size_t ws_size, hipStream_t stream) {
  const int* x = (const int*)d_in[0];
  const float* tok = (const float*)d_in[1];
  const float* pos = (const float*)d_in[2];
  const float* Wq = (const float*)d_in[3];
  const float* bq = (const float*)d_in[4];
  const float* Wk = (const float*)d_in[5];
  const float* bk = (const float*)d_in[6];
  const float* Wv = (const float*)d_in[7];
  const float* bv = (const float*)d_in[8];
  const float* Wo = (const float*)d_in[9];
  const float* bo = (const float*)d_in[10];
  const float* W1 = (const float*)d_in[11];
  const float* b1 = (const float*)d_in[12];
  const float* W2 = (const float*)d_in[13];
  const float* b2 = (const float*)d_in[14];
  float* out = (float*)d_out;

  char* ws = (char*)d_ws;
  constexpr size_t MB = 1ull << 20;
  float* h = (float*)(ws + 0);              // 16MB fp32 residual
  bf16_t* hb = (bf16_t*)(ws + 16 * MB);     // 8MB bf16 mirror of h
  bf16_t* qkv = (bf16_t*)(ws + 24 * MB);    // 24MB  [4096][3072]
  bf16_t* vT = (bf16_t*)(ws + 48 * MB);     // 8MB   [1024][4096]
  bf16_t* Ob = (bf16_t*)(ws + 56 * MB);     // 8MB   [4096][1024]
  float* S = (float*)(ws + 64 * MB);        // 64MB  [4096][4096]
  bf16_t* mh = (bf16_t*)(ws + 64 * MB);     // 32MB (aliases S; disjoint)
  bf16_t* P = (bf16_t*)(ws + 128 * MB);     // 32MB  [4096][4096]
  bf16_t* WqkvT = (bf16_t*)(ws + 160 * MB); // 6MB   [3072][1024]
  bf16_t* WoT = (bf16_t*)(ws + 166 * MB);   // 2MB
  bf16_t* W1T = (bf16_t*)(ws + 168 * MB);   // 8MB
  bf16_t* W2T = (bf16_t*)(ws + 176 * MB);   // 8MB
  float* bqkv = (float*)(ws + 184 * MB);    // 12KB

  embed_kernel<<<SEQ, 256, 0, stream>>>(x, tok, pos, h, hb);

  const dim3 tb(32, 8);
  for (int l = 0; l < NLAYER; ++l) {
    const float* lWq = Wq + (size_t)l * DIM * KEY;
    const float* lWk = Wk + (size_t)l * DIM * KEY;
    const float* lWv = Wv + (size_t)l * DIM * KEY;
    const float* lWo = Wo + (size_t)l * KEY * DIM;
    const float* lW1 = W1 + (size_t)l * DIM * MLP;
    const float* lW2 = W2 + (size_t)l * MLP * DIM;

    cvtT_qkv<<<dim3(KEY / 32, DIM / 32, 3), tb, 0, stream>>>(lWq, lWk, lWv, WqkvT);
    bias_cat3<<<12, 256, 0, stream>>>(bq + (size_t)l * KEY, bk + (size_t)l * KEY,
                                      bv + (size_t)l * KEY, bqkv);
    cvtT_kernel<<<dim3(DIM / 32, KEY / 32), tb, 0, stream>>>(lWo, WoT, KEY, DIM);
    cvtT_kernel<<<dim3(MLP / 32, DIM / 32), tb, 0, stream>>>(lW1, W1T, DIM, MLP);
    cvtT_kernel<<<dim3(DIM / 32, MLP / 32), tb, 0, stream>>>(lW2, W2T, MLP, DIM);

    // qkv = hb @ Wqkv^T + bqkv   [4096][3072]
    gemm_nt<1, 128><<<dim3(3 * KEY / 128, SEQ / 128), 256, 0, stream>>>(
        hb, DIM, WqkvT, DIM, qkv, 3 * KEY, bqkv, DIM, nullptr);

    const bf16_t* qb = qkv;
    const bf16_t* kb = qkv + KEY;
    const bf16_t* vb = qkv + 2 * KEY;

    transT_bf16<<<dim3(KEY / 32, SEQ / 32), tb, 0, stream>>>(vb, 3 * KEY, vT, SEQ, KEY);

    // S = Q K^T  [4096 x 4096] fp32
    gemm_nt<0, 128><<<dim3(SEQ / 128, SEQ / 128), 256, 0, stream>>>(
        qb, 3 * KEY, kb, 3 * KEY, S, SEQ, nullptr, KEY, nullptr);

    softmax_kernel<<<SEQ, 256, 0, stream>>>(S, P);

    // O = P V   (B = V^T [KEY][SEQ])
    gemm_nt<1, 64><<<dim3(KEY / 64, SEQ / 128), 256, 0, stream>>>(
        P, SEQ, vT, SEQ, Ob, KEY, nullptr, SEQ, nullptr);

    // h += O Wo + bo ; hb = bf16(h)
    gemm_nt<4, 64><<<dim3(DIM / 64, SEQ / 128), 256, 0, stream>>>(
        Ob, KEY, WoT, KEY, h, DIM, bo + (size_t)l * DIM, KEY, hb);

    // mh = relu(hb W1 + b1)
    gemm_nt<2, 128><<<dim3(MLP / 128, SEQ / 128), 256, 0, stream>>>(
        hb, DIM, W1T, DIM, mh, MLP, b1 + (size_t)l * MLP, DIM, nullptr);

    // h += mh W2 + b2 ; hb = bf16(h)
    gemm_nt<4, 64><<<dim3(DIM / 64, SEQ / 128), 256, 0, stream>>>(
        mh, MLP, W2T, MLP, h, DIM, b2 + (size_t)l * DIM, MLP, hb);
  }

  output_kernel<<<dim3((VOC / 4 + 255) / 256, SEQ), 256, 0, stream>>>(h, out);
}

// Round 3
// 2960.468 us; speedup vs baseline: 1.2661x; 1.0282x over previous
//
#include <hip/hip_runtime.h>
#include <hip/hip_bf16.h>
#include <stdint.h>

typedef __bf16 bf16_t;
typedef __bf16 bf16x8 __attribute__((ext_vector_type(8)));
typedef __bf16 bf16x4 __attribute__((ext_vector_type(4)));
typedef float f32x4 __attribute__((ext_vector_type(4)));

constexpr int SEQ = 4096;
constexpr int DIM = 1024;
constexpr int KEY = 1024;
constexpr int MLP = 4096;
constexpr int VOC = 32000;
constexpr int NLAYER = 8;

__device__ __forceinline__ void gld_lds16(const bf16_t* g, bf16_t* lds) {
  __builtin_amdgcn_global_load_lds(
      (__attribute__((address_space(1))) void*)g,
      (__attribute__((address_space(3))) void*)lds,
      16, 0, 0);
}

#define FENCE() asm volatile("" ::: "memory")
__device__ __forceinline__ void barrier_raw() {
  FENCE();
  __builtin_amdgcn_s_barrier();
  FENCE();
}
#define VMCNT(n) asm volatile("s_waitcnt vmcnt(" #n ")" ::: "memory")

// ============================================================================
// 256x256 8-phase GEMM (T2+T3+T4+T5): C[i,j] = sum_d A[i,d]*B[j,d] (+bias[j])
// A:[M][Kd] bf16 (lda), B:[N][Kd] bf16 (ldb). Kd multiple of 128.
// MODE 0: fp32 store; 1: bf16 store (+bias); 2: bf16 relu store (+bias)
// 512 threads = 8 waves. Per phase: one C-quadrant (128x128) x K=64.
// LDS: 2 buf x {A0,A1,B0,B1} halves of 128x64. Swizzle: 16B slot ^= (row&7).
// ============================================================================
template <int MODE>
__global__ __launch_bounds__(512) void gemm256(
    const bf16_t* __restrict__ Aop, int lda,
    const bf16_t* __restrict__ Bop, int ldb,
    void* __restrict__ Cp, int ldc,
    const float* __restrict__ bias, int Kd) {
  __shared__ __attribute__((aligned(16))) bf16_t LDS[2][4][128][64];
  const int t = threadIdx.x;
  const int l = t & 63;
  const int w = t >> 6;   // 0..7
  const int qr = w >> 2;  // 0..1: row-half within quadrant
  const int qc = w & 3;   // 0..3: col-quarter within quadrant
  const int brow = blockIdx.y * 256;
  const int bcol = blockIdx.x * 256;

  // staging geometry: per 8KB round, thread t -> row sr, physical slot t&7,
  // logical slot sl = (t&7) ^ (sr&7)  (pre-swizzled global source)
  const int sr = t >> 3;  // 0..63
  const int sl8 = (((t & 7) ^ (sr & 7)) * 8);
  const int sp8 = (t & 7) * 8;

  f32x4 acc[2][2][4][2] = {};  // [mh][nh][m][n]

  // stage half-tile `reg` (0=A0,1=A1,2=B0,3=B1) of K-tile `tile`
  auto STAGE = [&](int tile, int reg) {
    const int bufS = tile & 1;
    const bf16_t* src;
    size_t ld;
    int grow;
    if (reg < 2) {
      src = Aop; ld = (size_t)lda; grow = brow + reg * 128;
    } else {
      src = Bop; ld = (size_t)ldb; grow = bcol + (reg - 2) * 128;
    }
    const bf16_t* g0 = src + (size_t)(grow + sr) * ld + tile * 64 + sl8;
    bf16_t* d0 = &LDS[bufS][reg][sr][sp8];
    gld_lds16(g0, d0);
    gld_lds16(g0 + 64 * ld, d0 + 64 * 64);
  };

#define PHASE(MH, NH, STAGE_STMT, TAIL)                                       \
  {                                                                           \
    bf16x8 afr[4][2], bfr2[2][2];                                             \
    _Pragma("unroll") for (int m = 0; m < 4; ++m) {                           \
      const int r = qr * 64 + m * 16 + (l & 15);                              \
      _Pragma("unroll") for (int ks = 0; ks < 2; ++ks) {                      \
        const int s = (((ks * 4 + (l >> 4)) ^ (r & 7)) * 8);                  \
        afr[m][ks] = *(const bf16x8*)&LDS[buf][MH][r][s];                     \
      }                                                                       \
    }                                                                         \
    _Pragma("unroll") for (int n = 0; n < 2; ++n) {                           \
      const int c = qc * 32 + n * 16 + (l & 15);                              \
      _Pragma("unroll") for (int ks = 0; ks < 2; ++ks) {                      \
        const int s = (((ks * 4 + (l >> 4)) ^ (c & 7)) * 8);                  \
        bfr2[n][ks] = *(const bf16x8*)&LDS[buf][2 + NH][c][s];                \
      }                                                                       \
    }                                                                         \
    STAGE_STMT;                                                               \
    barrier_raw();                                                            \
    __builtin_amdgcn_s_setprio(1);                                            \
    _Pragma("unroll") for (int m = 0; m < 4; ++m)                             \
        _Pragma("unroll") for (int n = 0; n < 2; ++n)                         \
            _Pragma("unroll") for (int ks = 0; ks < 2; ++ks)                  \
                acc[MH][NH][m][n] = __builtin_amdgcn_mfma_f32_16x16x32_bf16(  \
                    afr[m][ks], bfr2[n][ks], acc[MH][NH][m][n], 0, 0, 0);     \
    __builtin_amdgcn_s_setprio(0);                                            \
    TAIL;                                                                     \
    barrier_raw();                                                            \
  }

  const int NT = Kd >> 6;
  // prologue: tile0 fully + tile1 A0,B0 (12 loads); drain to tile0 complete
  STAGE(0, 0); STAGE(0, 1); STAGE(0, 2); STAGE(0, 3);
  STAGE(1, 0); STAGE(1, 2);
  VMCNT(4);
  barrier_raw();

  for (int tt = 0; tt < NT; ++tt) {
    const int buf = tt & 1;
    const bool s1 = (tt + 1 < NT);
    const bool s2 = (tt + 2 < NT);
    PHASE(0, 0, if (s1) STAGE(tt + 1, 1), );
    PHASE(0, 1, if (s1) STAGE(tt + 1, 3), );
    PHASE(1, 0, if (s2) STAGE(tt + 2, 0), );
    PHASE(1, 1, if (s2) STAGE(tt + 2, 2),
          if (tt < NT - 2) { VMCNT(4); } else { VMCNT(0); });
  }
#undef PHASE

  // epilogue: C write (no LDS use)
#pragma unroll
  for (int mh = 0; mh < 2; ++mh)
#pragma unroll
    for (int nh = 0; nh < 2; ++nh)
#pragma unroll
      for (int m = 0; m < 4; ++m)
#pragma unroll
        for (int n = 0; n < 2; ++n) {
          const int col = bcol + nh * 128 + qc * 32 + n * 16 + (l & 15);
          const int row0 = brow + mh * 128 + qr * 64 + m * 16 + (l >> 4) * 4;
          const float bv = bias ? bias[col] : 0.0f;
#pragma unroll
          for (int r = 0; r < 4; ++r) {
            const float v = acc[mh][nh][m][n][r] + bv;
            const size_t idx = (size_t)(row0 + r) * ldc + col;
            if (MODE == 0)
              ((float*)Cp)[idx] = v;
            else if (MODE == 1)
              ((bf16_t*)Cp)[idx] = (bf16_t)v;
            else
              ((bf16_t*)Cp)[idx] = (bf16_t)fmaxf(v, 0.0f);
          }
        }
}

// ============================================================================
// 128xBN m97-structure GEMM (kept for N=1024 outputs: PV, proj, W2)
// MODE 1: bf16 store; MODE 4: fp32 Cp += v, Cb = bf16(new)
// ============================================================================
template <int MODE, int BN>
__global__ __launch_bounds__(256) void gemm_nt(
    const bf16_t* __restrict__ A, int lda,
    const bf16_t* __restrict__ B, int ldb,
    void* __restrict__ Cp, int ldc,
    const float* __restrict__ bias,
    int Kd, bf16_t* __restrict__ Cb) {
  __shared__ __attribute__((aligned(16))) bf16_t As[128 * 32];
  __shared__ __attribute__((aligned(16))) bf16_t Bs[BN * 32];
  const int t = threadIdx.x;
  const int l = t & 63;
  const int w = t >> 6;
  const int brow = blockIdx.y * 128;
  const int bcol = blockIdx.x * BN;
  const int wr = (w >> 1) * 64;
  const int wc = (w & 1) * (BN / 2);
  constexpr int NF = BN / 32;

  f32x4 acc[4][NF] = {};

  const int srow = t >> 2;
  const int scol = (t & 3) * 8;
  const bf16_t* Ag = A + (size_t)(brow + srow) * lda + scol;
  const bf16_t* Bg = B + (size_t)(bcol + srow) * ldb + scol;
  bf16_t* AsD = &As[t * 8];
  bf16_t* BsD = &Bs[t * 8];

  const int arow = wr + (l & 15);
  const int brw = wc + (l & 15);
  const int kq = (l >> 4) * 8;

  for (int kt = 0; kt < Kd; kt += 32) {
    if (kt) __syncthreads();
    gld_lds16(Ag + kt, AsD);
    gld_lds16(Ag + kt + (size_t)64 * lda, AsD + 2048);
    gld_lds16(Bg + kt, BsD);
    if (BN == 128) gld_lds16(Bg + kt + (size_t)64 * ldb, BsD + 2048);
    __syncthreads();
    bf16x8 af[4], bfr[NF];
#pragma unroll
    for (int mi = 0; mi < 4; ++mi)
      af[mi] = *(const bf16x8*)&As[(arow + mi * 16) * 32 + kq];
#pragma unroll
    for (int ni = 0; ni < NF; ++ni)
      bfr[ni] = *(const bf16x8*)&Bs[(brw + ni * 16) * 32 + kq];
#pragma unroll
    for (int mi = 0; mi < 4; ++mi)
#pragma unroll
      for (int ni = 0; ni < NF; ++ni)
        acc[mi][ni] = __builtin_amdgcn_mfma_f32_16x16x32_bf16(
            af[mi], bfr[ni], acc[mi][ni], 0, 0, 0);
  }

  const int crow0 = brow + wr + (l >> 4) * 4;
  const int ccol0 = bcol + wc + (l & 15);
#pragma unroll
  for (int mi = 0; mi < 4; ++mi) {
#pragma unroll
    for (int ni = 0; ni < NF; ++ni) {
      const int col = ccol0 + ni * 16;
      const float bv = bias ? bias[col] : 0.0f;
#pragma unroll
      for (int r = 0; r < 4; ++r) {
        const int row = crow0 + mi * 16 + r;
        const float v = acc[mi][ni][r] + bv;
        const size_t idx = (size_t)row * ldc + col;
        if (MODE == 1) {
          ((bf16_t*)Cp)[idx] = (bf16_t)v;
        } else {
          const float nv = ((float*)Cp)[idx] + v;
          ((float*)Cp)[idx] = nv;
          Cb[idx] = (bf16_t)nv;
        }
      }
    }
  }
}

// row-wise softmax over 4096 fp32 -> bf16
__global__ __launch_bounds__(256) void softmax_kernel(
    const float* __restrict__ S, bf16_t* __restrict__ P) {
  const int row = blockIdx.x;
  const int t = threadIdx.x;
  const float4* s4 = (const float4*)(S + (size_t)row * SEQ);
  float4 v[4];
  float mx = -3.0e38f;
#pragma unroll
  for (int j = 0; j < 4; ++j) {
    v[j] = s4[j * 256 + t];
    mx = fmaxf(mx, fmaxf(fmaxf(v[j].x, v[j].y), fmaxf(v[j].z, v[j].w)));
  }
#pragma unroll
  for (int off = 32; off >= 1; off >>= 1) mx = fmaxf(mx, __shfl_xor(mx, off));
  __shared__ float redm[4];
  __shared__ float reds[4];
  if ((t & 63) == 0) redm[t >> 6] = mx;
  __syncthreads();
  mx = fmaxf(fmaxf(redm[0], redm[1]), fmaxf(redm[2], redm[3]));
  float e[16];
  float sum = 0.0f;
#pragma unroll
  for (int j = 0; j < 4; ++j) {
    e[4 * j + 0] = __expf(v[j].x - mx);
    e[4 * j + 1] = __expf(v[j].y - mx);
    e[4 * j + 2] = __expf(v[j].z - mx);
    e[4 * j + 3] = __expf(v[j].w - mx);
    sum += e[4 * j + 0] + e[4 * j + 1] + e[4 * j + 2] + e[4 * j + 3];
  }
#pragma unroll
  for (int off = 32; off >= 1; off >>= 1) sum += __shfl_xor(sum, off);
  if ((t & 63) == 0) reds[t >> 6] = sum;
  __syncthreads();
  sum = reds[0] + reds[1] + reds[2] + reds[3];
  const float inv = 1.0f / sum;
  bf16x4* p4 = (bf16x4*)(P + (size_t)row * SEQ);
#pragma unroll
  for (int j = 0; j < 4; ++j) {
    bf16x4 o;
    o[0] = (bf16_t)(e[4 * j + 0] * inv);
    o[1] = (bf16_t)(e[4 * j + 1] * inv);
    o[2] = (bf16_t)(e[4 * j + 2] * inv);
    o[3] = (bf16_t)(e[4 * j + 3] * inv);
    p4[j * 256 + t] = o;
  }
}

// fp32 [R][C] -> bf16 [C][R] (transpose + convert)
__global__ void cvtT_kernel(const float* __restrict__ in,
                            bf16_t* __restrict__ out, int R, int C) {
  __shared__ float tile[32][33];
  const int c0 = blockIdx.x * 32, r0 = blockIdx.y * 32;
  const int x = threadIdx.x, y = threadIdx.y;
#pragma unroll
  for (int k = 0; k < 4; ++k)
    tile[y + 8 * k][x] = in[(size_t)(r0 + y + 8 * k) * C + c0 + x];
  __syncthreads();
#pragma unroll
  for (int k = 0; k < 4; ++k)
    out[(size_t)(c0 + y + 8 * k) * R + r0 + x] = (bf16_t)tile[x][y + 8 * k];
}

// batched: z selects Wq/Wk/Wv [D][K]; out rows z*K + [0,K)
__global__ void cvtT_qkv(const float* __restrict__ Wq,
                         const float* __restrict__ Wk,
                         const float* __restrict__ Wv,
                         bf16_t* __restrict__ out) {
  __shared__ float tile[32][33];
  const int z = blockIdx.z;
  const float* in = (z == 0) ? Wq : (z == 1) ? Wk : Wv;
  bf16_t* o = out + (size_t)z * KEY * DIM;
  const int c0 = blockIdx.x * 32, r0 = blockIdx.y * 32;
  const int x = threadIdx.x, y = threadIdx.y;
#pragma unroll
  for (int k = 0; k < 4; ++k)
    tile[y + 8 * k][x] = in[(size_t)(r0 + y + 8 * k) * KEY + c0 + x];
  __syncthreads();
#pragma unroll
  for (int k = 0; k < 4; ++k)
    o[(size_t)(c0 + y + 8 * k) * DIM + r0 + x] = (bf16_t)tile[x][y + 8 * k];
}

__global__ void bias_cat3(const float* __restrict__ a,
                          const float* __restrict__ b,
                          const float* __restrict__ c,
                          float* __restrict__ out) {
  const int i = blockIdx.x * 256 + threadIdx.x;
  if (i < KEY)
    out[i] = a[i];
  else if (i < 2 * KEY)
    out[i] = b[i - KEY];
  else if (i < 3 * KEY)
    out[i] = c[i - 2 * KEY];
}

// bf16 [R][C] (ldin) -> bf16 [C][R]
__global__ void transT_bf16(const bf16_t* __restrict__ in, int ldin,
                            bf16_t* __restrict__ out, int R, int C) {
  __shared__ bf16_t tile[32][33];
  const int c0 = blockIdx.x * 32, r0 = blockIdx.y * 32;
  const int x = threadIdx.x, y = threadIdx.y;
#pragma unroll
  for (int k = 0; k < 4; ++k)
    tile[y + 8 * k][x] = in[(size_t)(r0 + y + 8 * k) * ldin + c0 + x];
  __syncthreads();
#pragma unroll
  for (int k = 0; k < 4; ++k)
    out[(size_t)(c0 + y + 8 * k) * R + r0 + x] = tile[x][y + 8 * k];
}

__global__ __launch_bounds__(256) void embed_kernel(
    const int* __restrict__ x, const float* __restrict__ tok,
    const float* __restrict__ pos, float* __restrict__ h,
    bf16_t* __restrict__ hb) {
  const int n = blockIdx.x, t = threadIdx.x;
  const int id = x[n];
  const float4 a = ((const float4*)(tok + (size_t)id * DIM))[t];
  const float4 b = ((const float4*)(pos + (size_t)n * DIM))[t];
  float4 o;
  o.x = a.x + b.x;
  o.y = a.y + b.y;
  o.z = a.z + b.z;
  o.w = a.w + b.w;
  ((float4*)(h + (size_t)n * DIM))[t] = o;
  bf16x4 ob;
  ob[0] = (bf16_t)o.x;
  ob[1] = (bf16_t)o.y;
  ob[2] = (bf16_t)o.z;
  ob[3] = (bf16_t)o.w;
  ((bf16x4*)(hb + (size_t)n * DIM))[t] = ob;
}

// out[n,v] = v < DIM ? h[n,v] : 0   (unembed is eye(D,V))
__global__ __launch_bounds__(256) void output_kernel(
    const float* __restrict__ h, float* __restrict__ out) {
  const int n = blockIdx.y;
  const int i4 = blockIdx.x * 256 + threadIdx.x;
  if (i4 >= VOC / 4) return;
  float4 v = make_float4(0.0f, 0.0f, 0.0f, 0.0f);
  if (i4 < DIM / 4) v = ((const float4*)(h + (size_t)n * DIM))[i4];
  ((float4*)(out + (size_t)n * VOC))[i4] = v;
}

extern "C" void kernel_launch(void* const* d_in, const int* in_sizes, int n_in,
                              void* d_out, int out_size, void* d_ws,
                              size_t ws_size, hipStream_t stream) {
  const int* x = (const int*)d_in[0];
  const float* tok = (const float*)d_in[1];
  const float* pos = (const float*)d_in[2];
  const float* Wq = (const float*)d_in[3];
  const float* bq = (const float*)d_in[4];
  const float* Wk = (const float*)d_in[5];
  const float* bk = (const float*)d_in[6];
  const float* Wv = (const float*)d_in[7];
  const float* bv = (const float*)d_in[8];
  const float* Wo = (const float*)d_in[9];
  const float* bo = (const float*)d_in[10];
  const float* W1 = (const float*)d_in[11];
  const float* b1 = (const float*)d_in[12];
  const float* W2 = (const float*)d_in[13];
  const float* b2 = (const float*)d_in[14];
  float* out = (float*)d_out;

  char* ws = (char*)d_ws;
  constexpr size_t MB = 1ull << 20;
  float* h = (float*)(ws + 0);              // 16MB fp32 residual
  bf16_t* hb = (bf16_t*)(ws + 16 * MB);     // 8MB bf16 mirror of h
  bf16_t* qkv = (bf16_t*)(ws + 24 * MB);    // 24MB  [4096][3072]
  bf16_t* vT = (bf16_t*)(ws + 48 * MB);     // 8MB   [1024][4096]
  bf16_t* Ob = (bf16_t*)(ws + 56 * MB);     // 8MB   [4096][1024]
  float* S = (float*)(ws + 64 * MB);        // 64MB  [4096][4096]
  bf16_t* mh = (bf16_t*)(ws + 64 * MB);     // 32MB (aliases S; disjoint)
  bf16_t* P = (bf16_t*)(ws + 128 * MB);     // 32MB  [4096][4096]
  bf16_t* WqkvT = (bf16_t*)(ws + 160 * MB); // 6MB   [3072][1024]
  bf16_t* WoT = (bf16_t*)(ws + 166 * MB);   // 2MB
  bf16_t* W1T = (bf16_t*)(ws + 168 * MB);   // 8MB
  bf16_t* W2T = (bf16_t*)(ws + 176 * MB);   // 8MB
  float* bqkv = (float*)(ws + 184 * MB);    // 12KB

  embed_kernel<<<SEQ, 256, 0, stream>>>(x, tok, pos, h, hb);

  const dim3 tb(32, 8);
  for (int l = 0; l < NLAYER; ++l) {
    const float* lWq = Wq + (size_t)l * DIM * KEY;
    const float* lWk = Wk + (size_t)l * DIM * KEY;
    const float* lWv = Wv + (size_t)l * DIM * KEY;
    const float* lWo = Wo + (size_t)l * KEY * DIM;
    const float* lW1 = W1 + (size_t)l * DIM * MLP;
    const float* lW2 = W2 + (size_t)l * MLP * DIM;

    cvtT_qkv<<<dim3(KEY / 32, DIM / 32, 3), tb, 0, stream>>>(lWq, lWk, lWv, WqkvT);
    bias_cat3<<<12, 256, 0, stream>>>(bq + (size_t)l * KEY, bk + (size_t)l * KEY,
                                      bv + (size_t)l * KEY, bqkv);
    cvtT_kernel<<<dim3(DIM / 32, KEY / 32), tb, 0, stream>>>(lWo, WoT, KEY, DIM);
    cvtT_kernel<<<dim3(MLP / 32, DIM / 32), tb, 0, stream>>>(lW1, W1T, DIM, MLP);
    cvtT_kernel<<<dim3(DIM / 32, MLP / 32), tb, 0, stream>>>(lW2, W2T, MLP, DIM);

    // qkv = hb @ Wqkv^T + bqkv   [4096][3072]  (8-phase 256^2)
    gemm256<1><<<dim3(3 * KEY / 256, SEQ / 256), 512, 0, stream>>>(
        hb, DIM, WqkvT, DIM, qkv, 3 * KEY, bqkv, DIM);

    const bf16_t* qb = qkv;
    const bf16_t* kb = qkv + KEY;
    const bf16_t* vb = qkv + 2 * KEY;

    transT_bf16<<<dim3(KEY / 32, SEQ / 32), tb, 0, stream>>>(vb, 3 * KEY, vT, SEQ, KEY);

    // S = Q K^T  [4096 x 4096] fp32  (8-phase 256^2)
    gemm256<0><<<dim3(SEQ / 256, SEQ / 256), 512, 0, stream>>>(
        qb, 3 * KEY, kb, 3 * KEY, S, SEQ, nullptr, KEY);

    softmax_kernel<<<SEQ, 256, 0, stream>>>(S, P);

    // O = P V   (B = V^T [KEY][SEQ])
    gemm_nt<1, 64><<<dim3(KEY / 64, SEQ / 128), 256, 0, stream>>>(
        P, SEQ, vT, SEQ, Ob, KEY, nullptr, SEQ, nullptr);

    // h += O Wo + bo ; hb = bf16(h)
    gemm_nt<4, 64><<<dim3(DIM / 64, SEQ / 128), 256, 0, stream>>>(
        Ob, KEY, WoT, KEY, h, DIM, bo + (size_t)l * DIM, KEY, hb);

    // mh = relu(hb W1 + b1)   (8-phase 256^2)
    gemm256<2><<<dim3(MLP / 256, SEQ / 256), 512, 0, stream>>>(
        hb, DIM, W1T, DIM, mh, MLP, b1 + (size_t)l * MLP, DIM);

    // h += mh W2 + b2 ; hb = bf16(h)
    gemm_nt<4, 64><<<dim3(DIM / 64, SEQ / 128), 256, 0, stream>>>(
        mh, MLP, W2T, MLP, h, DIM, b2 + (size_t)l * DIM, MLP, hb);
  }

  output_kernel<<<dim3((VOC / 4 + 255) / 256, SEQ), 256, 0, stream>>>(h, out);
}

// Round 4
// 2795.266 us; speedup vs baseline: 1.3409x; 1.0591x over previous
//
#include <hip/hip_runtime.h>
#include <hip/hip_bf16.h>
#include <stdint.h>

typedef __bf16 bf16_t;
typedef __bf16 bf16x8 __attribute__((ext_vector_type(8)));
typedef __bf16 bf16x4 __attribute__((ext_vector_type(4)));
typedef float f32x4 __attribute__((ext_vector_type(4)));

constexpr int SEQ = 4096;
constexpr int DIM = 1024;
constexpr int KEY = 1024;
constexpr int MLP = 4096;
constexpr int VOC = 32000;
constexpr int NLAYER = 8;

__device__ __forceinline__ void gld_lds16(const bf16_t* g, bf16_t* lds) {
  __builtin_amdgcn_global_load_lds(
      (__attribute__((address_space(1))) void*)g,
      (__attribute__((address_space(3))) void*)lds,
      16, 0, 0);
}

#define FENCE() asm volatile("" ::: "memory")
__device__ __forceinline__ void barrier_raw() {
  FENCE();
  __builtin_amdgcn_s_barrier();
  FENCE();
}
#define VMCNT(n) asm volatile("s_waitcnt vmcnt(" #n ")" ::: "memory")
#define LGKMCNT(n) asm volatile("s_waitcnt lgkmcnt(" #n ")" ::: "memory")

__device__ __forceinline__ void xcd_swizzle(int& bx, int& by) {
  const int gx = gridDim.x;
  const int nwg = gx * gridDim.y;
  if ((nwg & 7) == 0) {
    int id = by * gx + bx;
    const int per = nwg >> 3;
    id = (id & 7) * per + (id >> 3);
    bx = id % gx;
    by = id / gx;
  }
}

// ============================================================================
// 256x256 8-phase GEMM (T2+T3+T4+T5): C[i,j] = sum_d A[i,d]*B[j,d] (+bias[j])
// A:[M][Kd] bf16 (lda), B:[N][Kd] bf16 (ldb). Kd multiple of 128.
// MODE 0: fp32 store; 1: bf16 store (+bias); 2: bf16 relu store (+bias)
// 512 threads = 8 waves. Per phase: one C-quadrant (128x128) x K=64.
// Fragment reads deduped: 24 ds_read_b128/wave/K-tile (12/4/8/0 per phase),
// A-half and both B-halves held in registers across phases.
// LDS: 2 buf x {A0,A1,B0,B1} halves of 128x64. Swizzle: 16B slot ^= (row&7).
// ============================================================================
template <int MODE>
__global__ __launch_bounds__(512) void gemm256(
    const bf16_t* __restrict__ Aop, int lda,
    const bf16_t* __restrict__ Bop, int ldb,
    void* __restrict__ Cp, int ldc,
    const float* __restrict__ bias, int Kd) {
  __shared__ __attribute__((aligned(16))) bf16_t LDS[2][4][128][64];
  const int t = threadIdx.x;
  const int l = t & 63;
  const int w = t >> 6;   // 0..7
  const int qr = w >> 2;  // 0..1: row-half within quadrant
  const int qc = w & 3;   // 0..3: col-quarter within quadrant
  int bxs = blockIdx.x, bys = blockIdx.y;
  xcd_swizzle(bxs, bys);
  const int brow = bys * 256;
  const int bcol = bxs * 256;

  // staging geometry: per 8KB round, thread t -> row sr, physical slot t&7,
  // logical slot sl = (t&7) ^ (sr&7)  (pre-swizzled global source)
  const int sr = t >> 3;  // 0..63
  const int sl8 = (((t & 7) ^ (sr & 7)) * 8);
  const int sp8 = (t & 7) * 8;

  f32x4 acc[2][2][4][2] = {};  // [mh][nh][m][n]
  bf16x8 afr[4][2];            // current A-half fragments
  bf16x8 bfr[2][2][2];         // [half][n][ks] — both B-halves live

  // stage half-tile `reg` (0=A0,1=A1,2=B0,3=B1) of K-tile `tile`
  auto STAGE = [&](int tile, int reg) {
    const int bufS = tile & 1;
    const bf16_t* src;
    size_t ld;
    int grow;
    if (reg < 2) {
      src = Aop; ld = (size_t)lda; grow = brow + reg * 128;
    } else {
      src = Bop; ld = (size_t)ldb; grow = bcol + (reg - 2) * 128;
    }
    const bf16_t* g0 = src + (size_t)(grow + sr) * ld + tile * 64 + sl8;
    bf16_t* d0 = &LDS[bufS][reg][sr][sp8];
    gld_lds16(g0, d0);
    gld_lds16(g0 + 64 * ld, d0 + 64 * 64);
  };

#define READ_A(buf, half)                                          \
  _Pragma("unroll") for (int m = 0; m < 4; ++m) {                  \
    const int r = qr * 64 + m * 16 + (l & 15);                     \
    _Pragma("unroll") for (int ks = 0; ks < 2; ++ks) {             \
      const int s = (((ks * 4 + (l >> 4)) ^ (r & 7)) * 8);         \
      afr[m][ks] = *(const bf16x8*)&LDS[buf][half][r][s];          \
    }                                                              \
  }
#define READ_B(buf, half)                                          \
  _Pragma("unroll") for (int n = 0; n < 2; ++n) {                  \
    const int c = qc * 32 + n * 16 + (l & 15);                     \
    _Pragma("unroll") for (int ks = 0; ks < 2; ++ks) {             \
      const int s = (((ks * 4 + (l >> 4)) ^ (c & 7)) * 8);         \
      bfr[half][n][ks] = *(const bf16x8*)&LDS[buf][2 + half][c][s];\
    }                                                              \
  }
#define MFMA_Q(MH, NH, BH)                                                  \
  __builtin_amdgcn_s_setprio(1);                                            \
  _Pragma("unroll") for (int m = 0; m < 4; ++m)                             \
      _Pragma("unroll") for (int n = 0; n < 2; ++n)                         \
          _Pragma("unroll") for (int ks = 0; ks < 2; ++ks)                  \
              acc[MH][NH][m][n] = __builtin_amdgcn_mfma_f32_16x16x32_bf16(  \
                  afr[m][ks], bfr[BH][n][ks], acc[MH][NH][m][n], 0, 0, 0);  \
  __builtin_amdgcn_s_setprio(0);

  const int NT = Kd >> 6;
  // prologue: tile0 fully + tile1 A0,B0 (12 loads); drain to tile0 complete
  STAGE(0, 0); STAGE(0, 1); STAGE(0, 2); STAGE(0, 3);
  STAGE(1, 0); STAGE(1, 2);
  VMCNT(4);
  barrier_raw();

  for (int tt = 0; tt < NT; ++tt) {
    const int buf = tt & 1;
    const bool s1 = (tt + 1 < NT);
    const bool s2 = (tt + 2 < NT);

    // phase 1: read A0,B0 (12); q(0,0); stage (tt+1, A1)
    READ_A(buf, 0);
    READ_B(buf, 0);
    if (s1) STAGE(tt + 1, 1);
    LGKMCNT(8);
    barrier_raw();
    LGKMCNT(0);
    MFMA_Q(0, 0, 0);
    barrier_raw();

    // phase 2: read B1 (4); q(0,1) reusing A0; stage (tt+1, B1)
    READ_B(buf, 1);
    if (s1) STAGE(tt + 1, 3);
    barrier_raw();
    LGKMCNT(0);
    MFMA_Q(0, 1, 1);
    barrier_raw();

    // phase 3: read A1 (8); q(1,0) reusing B0; stage (tt+2, A0)
    READ_A(buf, 1);
    if (s2) STAGE(tt + 2, 0);
    barrier_raw();
    LGKMCNT(0);
    MFMA_Q(1, 0, 0);
    barrier_raw();

    // phase 4: no reads; q(1,1) reusing A1,B1; stage (tt+2, B0); vmcnt
    if (s2) STAGE(tt + 2, 2);
    barrier_raw();
    MFMA_Q(1, 1, 1);
    if (tt < NT - 2) { VMCNT(4); } else { VMCNT(0); }
    barrier_raw();
  }
#undef READ_A
#undef READ_B
#undef MFMA_Q

  // epilogue: C write (no LDS use)
#pragma unroll
  for (int mh = 0; mh < 2; ++mh)
#pragma unroll
    for (int nh = 0; nh < 2; ++nh)
#pragma unroll
      for (int m = 0; m < 4; ++m)
#pragma unroll
        for (int n = 0; n < 2; ++n) {
          const int col = bcol + nh * 128 + qc * 32 + n * 16 + (l & 15);
          const int row0 = brow + mh * 128 + qr * 64 + m * 16 + (l >> 4) * 4;
          const float bv = bias ? bias[col] : 0.0f;
#pragma unroll
          for (int r = 0; r < 4; ++r) {
            const float v = acc[mh][nh][m][n][r] + bv;
            const size_t idx = (size_t)(row0 + r) * ldc + col;
            if (MODE == 0)
              ((float*)Cp)[idx] = v;
            else if (MODE == 1)
              ((bf16_t*)Cp)[idx] = (bf16_t)v;
            else
              ((bf16_t*)Cp)[idx] = (bf16_t)fmaxf(v, 0.0f);
          }
        }
}

// ============================================================================
// 128xBN m97-structure GEMM (kept for N=1024 outputs: PV, proj, W2)
// MODE 1: bf16 store; MODE 4: fp32 Cp += v, Cb = bf16(new)
// ============================================================================
template <int MODE, int BN>
__global__ __launch_bounds__(256) void gemm_nt(
    const bf16_t* __restrict__ A, int lda,
    const bf16_t* __restrict__ B, int ldb,
    void* __restrict__ Cp, int ldc,
    const float* __restrict__ bias,
    int Kd, bf16_t* __restrict__ Cb) {
  __shared__ __attribute__((aligned(16))) bf16_t As[128 * 32];
  __shared__ __attribute__((aligned(16))) bf16_t Bs[BN * 32];
  const int t = threadIdx.x;
  const int l = t & 63;
  const int w = t >> 6;
  int bxs = blockIdx.x, bys = blockIdx.y;
  xcd_swizzle(bxs, bys);
  const int brow = bys * 128;
  const int bcol = bxs * BN;
  const int wr = (w >> 1) * 64;
  const int wc = (w & 1) * (BN / 2);
  constexpr int NF = BN / 32;

  f32x4 acc[4][NF] = {};

  const int srow = t >> 2;
  const int scol = (t & 3) * 8;
  const bf16_t* Ag = A + (size_t)(brow + srow) * lda + scol;
  const bf16_t* Bg = B + (size_t)(bcol + srow) * ldb + scol;
  bf16_t* AsD = &As[t * 8];
  bf16_t* BsD = &Bs[t * 8];

  const int arow = wr + (l & 15);
  const int brw = wc + (l & 15);
  const int kq = (l >> 4) * 8;

  for (int kt = 0; kt < Kd; kt += 32) {
    if (kt) __syncthreads();
    gld_lds16(Ag + kt, AsD);
    gld_lds16(Ag + kt + (size_t)64 * lda, AsD + 2048);
    gld_lds16(Bg + kt, BsD);
    if (BN == 128) gld_lds16(Bg + kt + (size_t)64 * ldb, BsD + 2048);
    __syncthreads();
    bf16x8 af[4], bfr[NF];
#pragma unroll
    for (int mi = 0; mi < 4; ++mi)
      af[mi] = *(const bf16x8*)&As[(arow + mi * 16) * 32 + kq];
#pragma unroll
    for (int ni = 0; ni < NF; ++ni)
      bfr[ni] = *(const bf16x8*)&Bs[(brw + ni * 16) * 32 + kq];
#pragma unroll
    for (int mi = 0; mi < 4; ++mi)
#pragma unroll
      for (int ni = 0; ni < NF; ++ni)
        acc[mi][ni] = __builtin_amdgcn_mfma_f32_16x16x32_bf16(
            af[mi], bfr[ni], acc[mi][ni], 0, 0, 0);
  }

  const int crow0 = brow + wr + (l >> 4) * 4;
  const int ccol0 = bcol + wc + (l & 15);
#pragma unroll
  for (int mi = 0; mi < 4; ++mi) {
#pragma unroll
    for (int ni = 0; ni < NF; ++ni) {
      const int col = ccol0 + ni * 16;
      const float bv = bias ? bias[col] : 0.0f;
#pragma unroll
      for (int r = 0; r < 4; ++r) {
        const int row = crow0 + mi * 16 + r;
        const float v = acc[mi][ni][r] + bv;
        const size_t idx = (size_t)row * ldc + col;
        if (MODE == 1) {
          ((bf16_t*)Cp)[idx] = (bf16_t)v;
        } else {
          const float nv = ((float*)Cp)[idx] + v;
          ((float*)Cp)[idx] = nv;
          Cb[idx] = (bf16_t)nv;
        }
      }
    }
  }
}

// row-wise softmax over 4096 fp32 -> bf16
__global__ __launch_bounds__(256) void softmax_kernel(
    const float* __restrict__ S, bf16_t* __restrict__ P) {
  const int row = blockIdx.x;
  const int t = threadIdx.x;
  const float4* s4 = (const float4*)(S + (size_t)row * SEQ);
  float4 v[4];
  float mx = -3.0e38f;
#pragma unroll
  for (int j = 0; j < 4; ++j) {
    v[j] = s4[j * 256 + t];
    mx = fmaxf(mx, fmaxf(fmaxf(v[j].x, v[j].y), fmaxf(v[j].z, v[j].w)));
  }
#pragma unroll
  for (int off = 32; off >= 1; off >>= 1) mx = fmaxf(mx, __shfl_xor(mx, off));
  __shared__ float redm[4];
  __shared__ float reds[4];
  if ((t & 63) == 0) redm[t >> 6] = mx;
  __syncthreads();
  mx = fmaxf(fmaxf(redm[0], redm[1]), fmaxf(redm[2], redm[3]));
  float e[16];
  float sum = 0.0f;
#pragma unroll
  for (int j = 0; j < 4; ++j) {
    e[4 * j + 0] = __expf(v[j].x - mx);
    e[4 * j + 1] = __expf(v[j].y - mx);
    e[4 * j + 2] = __expf(v[j].z - mx);
    e[4 * j + 3] = __expf(v[j].w - mx);
    sum += e[4 * j + 0] + e[4 * j + 1] + e[4 * j + 2] + e[4 * j + 3];
  }
#pragma unroll
  for (int off = 32; off >= 1; off >>= 1) sum += __shfl_xor(sum, off);
  if ((t & 63) == 0) reds[t >> 6] = sum;
  __syncthreads();
  sum = reds[0] + reds[1] + reds[2] + reds[3];
  const float inv = 1.0f / sum;
  bf16x4* p4 = (bf16x4*)(P + (size_t)row * SEQ);
#pragma unroll
  for (int j = 0; j < 4; ++j) {
    bf16x4 o;
    o[0] = (bf16_t)(e[4 * j + 0] * inv);
    o[1] = (bf16_t)(e[4 * j + 1] * inv);
    o[2] = (bf16_t)(e[4 * j + 2] * inv);
    o[3] = (bf16_t)(e[4 * j + 3] * inv);
    p4[j * 256 + t] = o;
  }
}

// fp32 [R][C] -> bf16 [C][R] (transpose + convert)
__global__ void cvtT_kernel(const float* __restrict__ in,
                            bf16_t* __restrict__ out, int R, int C) {
  __shared__ float tile[32][33];
  const int c0 = blockIdx.x * 32, r0 = blockIdx.y * 32;
  const int x = threadIdx.x, y = threadIdx.y;
#pragma unroll
  for (int k = 0; k < 4; ++k)
    tile[y + 8 * k][x] = in[(size_t)(r0 + y + 8 * k) * C + c0 + x];
  __syncthreads();
#pragma unroll
  for (int k = 0; k < 4; ++k)
    out[(size_t)(c0 + y + 8 * k) * R + r0 + x] = (bf16_t)tile[x][y + 8 * k];
}

// batched: z selects Wq/Wk/Wv [D][K]; out rows z*K + [0,K)
__global__ void cvtT_qkv(const float* __restrict__ Wq,
                         const float* __restrict__ Wk,
                         const float* __restrict__ Wv,
                         bf16_t* __restrict__ out) {
  __shared__ float tile[32][33];
  const int z = blockIdx.z;
  const float* in = (z == 0) ? Wq : (z == 1) ? Wk : Wv;
  bf16_t* o = out + (size_t)z * KEY * DIM;
  const int c0 = blockIdx.x * 32, r0 = blockIdx.y * 32;
  const int x = threadIdx.x, y = threadIdx.y;
#pragma unroll
  for (int k = 0; k < 4; ++k)
    tile[y + 8 * k][x] = in[(size_t)(r0 + y + 8 * k) * KEY + c0 + x];
  __syncthreads();
#pragma unroll
  for (int k = 0; k < 4; ++k)
    o[(size_t)(c0 + y + 8 * k) * DIM + r0 + x] = (bf16_t)tile[x][y + 8 * k];
}

__global__ void bias_cat3(const float* __restrict__ a,
                          const float* __restrict__ b,
                          const float* __restrict__ c,
                          float* __restrict__ out) {
  const int i = blockIdx.x * 256 + threadIdx.x;
  if (i < KEY)
    out[i] = a[i];
  else if (i < 2 * KEY)
    out[i] = b[i - KEY];
  else if (i < 3 * KEY)
    out[i] = c[i - 2 * KEY];
}

// bf16 [R][C] (ldin) -> bf16 [C][R]
__global__ void transT_bf16(const bf16_t* __restrict__ in, int ldin,
                            bf16_t* __restrict__ out, int R, int C) {
  __shared__ bf16_t tile[32][33];
  const int c0 = blockIdx.x * 32, r0 = blockIdx.y * 32;
  const int x = threadIdx.x, y = threadIdx.y;
#pragma unroll
  for (int k = 0; k < 4; ++k)
    tile[y + 8 * k][x] = in[(size_t)(r0 + y + 8 * k) * ldin + c0 + x];
  __syncthreads();
#pragma unroll
  for (int k = 0; k < 4; ++k)
    out[(size_t)(c0 + y + 8 * k) * R + r0 + x] = tile[x][y + 8 * k];
}

__global__ __launch_bounds__(256) void embed_kernel(
    const int* __restrict__ x, const float* __restrict__ tok,
    const float* __restrict__ pos, float* __restrict__ h,
    bf16_t* __restrict__ hb) {
  const int n = blockIdx.x, t = threadIdx.x;
  const int id = x[n];
  const float4 a = ((const float4*)(tok + (size_t)id * DIM))[t];
  const float4 b = ((const float4*)(pos + (size_t)n * DIM))[t];
  float4 o;
  o.x = a.x + b.x;
  o.y = a.y + b.y;
  o.z = a.z + b.z;
  o.w = a.w + b.w;
  ((float4*)(h + (size_t)n * DIM))[t] = o;
  bf16x4 ob;
  ob[0] = (bf16_t)o.x;
  ob[1] = (bf16_t)o.y;
  ob[2] = (bf16_t)o.z;
  ob[3] = (bf16_t)o.w;
  ((bf16x4*)(hb + (size_t)n * DIM))[t] = ob;
}

// out[n,v] = v < DIM ? h[n,v] : 0   (unembed is eye(D,V))
__global__ __launch_bounds__(256) void output_kernel(
    const float* __restrict__ h, float* __restrict__ out) {
  const int n = blockIdx.y;
  const int i4 = blockIdx.x * 256 + threadIdx.x;
  if (i4 >= VOC / 4) return;
  float4 v = make_float4(0.0f, 0.0f, 0.0f, 0.0f);
  if (i4 < DIM / 4) v = ((const float4*)(h + (size_t)n * DIM))[i4];
  ((float4*)(out + (size_t)n * VOC))[i4] = v;
}

extern "C" void kernel_launch(void* const* d_in, const int* in_sizes, int n_in,
                              void* d_out, int out_size, void* d_ws,
                              size_t ws_size, hipStream_t stream) {
  const int* x = (const int*)d_in[0];
  const float* tok = (const float*)d_in[1];
  const float* pos = (const float*)d_in[2];
  const float* Wq = (const float*)d_in[3];
  const float* bq = (const float*)d_in[4];
  const float* Wk = (const float*)d_in[5];
  const float* bk = (const float*)d_in[6];
  const float* Wv = (const float*)d_in[7];
  const float* bv = (const float*)d_in[8];
  const float* Wo = (const float*)d_in[9];
  const float* bo = (const float*)d_in[10];
  const float* W1 = (const float*)d_in[11];
  const float* b1 = (const float*)d_in[12];
  const float* W2 = (const float*)d_in[13];
  const float* b2 = (const float*)d_in[14];
  float* out = (float*)d_out;

  char* ws = (char*)d_ws;
  constexpr size_t MB = 1ull << 20;
  float* h = (float*)(ws + 0);              // 16MB fp32 residual
  bf16_t* hb = (bf16_t*)(ws + 16 * MB);     // 8MB bf16 mirror of h
  bf16_t* qkv = (bf16_t*)(ws + 24 * MB);    // 24MB  [4096][3072]
  bf16_t* vT = (bf16_t*)(ws + 48 * MB);     // 8MB   [1024][4096]
  bf16_t* Ob = (bf16_t*)(ws + 56 * MB);     // 8MB   [4096][1024]
  float* S = (float*)(ws + 64 * MB);        // 64MB  [4096][4096]
  bf16_t* mh = (bf16_t*)(ws + 64 * MB);     // 32MB (aliases S; disjoint)
  bf16_t* P = (bf16_t*)(ws + 128 * MB);     // 32MB  [4096][4096]
  bf16_t* WqkvT = (bf16_t*)(ws + 160 * MB); // 6MB   [3072][1024]
  bf16_t* WoT = (bf16_t*)(ws + 166 * MB);   // 2MB
  bf16_t* W1T = (bf16_t*)(ws + 168 * MB);   // 8MB
  bf16_t* W2T = (bf16_t*)(ws + 176 * MB);   // 8MB
  float* bqkv = (float*)(ws + 184 * MB);    // 12KB

  embed_kernel<<<SEQ, 256, 0, stream>>>(x, tok, pos, h, hb);

  const dim3 tb(32, 8);
  for (int l = 0; l < NLAYER; ++l) {
    const float* lWq = Wq + (size_t)l * DIM * KEY;
    const float* lWk = Wk + (size_t)l * DIM * KEY;
    const float* lWv = Wv + (size_t)l * DIM * KEY;
    const float* lWo = Wo + (size_t)l * KEY * DIM;
    const float* lW1 = W1 + (size_t)l * DIM * MLP;
    const float* lW2 = W2 + (size_t)l * MLP * DIM;

    cvtT_qkv<<<dim3(KEY / 32, DIM / 32, 3), tb, 0, stream>>>(lWq, lWk, lWv, WqkvT);
    bias_cat3<<<12, 256, 0, stream>>>(bq + (size_t)l * KEY, bk + (size_t)l * KEY,
                                      bv + (size_t)l * KEY, bqkv);
    cvtT_kernel<<<dim3(DIM / 32, KEY / 32), tb, 0, stream>>>(lWo, WoT, KEY, DIM);
    cvtT_kernel<<<dim3(MLP / 32, DIM / 32), tb, 0, stream>>>(lW1, W1T, DIM, MLP);
    cvtT_kernel<<<dim3(DIM / 32, MLP / 32), tb, 0, stream>>>(lW2, W2T, MLP, DIM);

    // qkv = hb @ Wqkv^T + bqkv   [4096][3072]  (8-phase 256^2)
    gemm256<1><<<dim3(3 * KEY / 256, SEQ / 256), 512, 0, stream>>>(
        hb, DIM, WqkvT, DIM, qkv, 3 * KEY, bqkv, DIM);

    const bf16_t* qb = qkv;
    const bf16_t* kb = qkv + KEY;
    const bf16_t* vb = qkv + 2 * KEY;

    transT_bf16<<<dim3(KEY / 32, SEQ / 32), tb, 0, stream>>>(vb, 3 * KEY, vT, SEQ, KEY);

    // S = Q K^T  [4096 x 4096] fp32  (8-phase 256^2)
    gemm256<0><<<dim3(SEQ / 256, SEQ / 256), 512, 0, stream>>>(
        qb, 3 * KEY, kb, 3 * KEY, S, SEQ, nullptr, KEY);

    softmax_kernel<<<SEQ, 256, 0, stream>>>(S, P);

    // O = P V   (B = V^T [KEY][SEQ])
    gemm_nt<1, 64><<<dim3(KEY / 64, SEQ / 128), 256, 0, stream>>>(
        P, SEQ, vT, SEQ, Ob, KEY, nullptr, SEQ, nullptr);

    // h += O Wo + bo ; hb = bf16(h)
    gemm_nt<4, 64><<<dim3(DIM / 64, SEQ / 128), 256, 0, stream>>>(
        Ob, KEY, WoT, KEY, h, DIM, bo + (size_t)l * DIM, KEY, hb);

    // mh = relu(hb W1 + b1)   (8-phase 256^2)
    gemm256<2><<<dim3(MLP / 256, SEQ / 256), 512, 0, stream>>>(
        hb, DIM, W1T, DIM, mh, MLP, b1 + (size_t)l * MLP, DIM);

    // h += mh W2 + b2 ; hb = bf16(h)
    gemm_nt<4, 64><<<dim3(DIM / 64, SEQ / 128), 256, 0, stream>>>(
        mh, MLP, W2T, MLP, h, DIM, b2 + (size_t)l * DIM, MLP, hb);
  }

  output_kernel<<<dim3((VOC / 4 + 255) / 256, SEQ), 256, 0, stream>>>(h, out);
}

// Round 5
// 2554.240 us; speedup vs baseline: 1.4674x; 1.0944x over previous
//
#include <hip/hip_runtime.h>
#include <hip/hip_bf16.h>
#include <stdint.h>

typedef __bf16 bf16_t;
typedef __bf16 bf16x8 __attribute__((ext_vector_type(8)));
typedef __bf16 bf16x4 __attribute__((ext_vector_type(4)));
typedef float f32x4 __attribute__((ext_vector_type(4)));

constexpr int SEQ = 4096;
constexpr int DIM = 1024;
constexpr int KEY = 1024;
constexpr int MLP = 4096;
constexpr int VOC = 32000;
constexpr int NLAYER = 8;

__device__ __forceinline__ void gld_lds16(const bf16_t* g, bf16_t* lds) {
  __builtin_amdgcn_global_load_lds(
      (__attribute__((address_space(1))) void*)g,
      (__attribute__((address_space(3))) void*)lds,
      16, 0, 0);
}

#define FENCE() asm volatile("" ::: "memory")
__device__ __forceinline__ void barrier_raw() {
  FENCE();
  __builtin_amdgcn_s_barrier();
  FENCE();
}
#define VMCNT(n) asm volatile("s_waitcnt vmcnt(" #n ")" ::: "memory")
#define LGKMCNT(n) asm volatile("s_waitcnt lgkmcnt(" #n ")" ::: "memory")

__device__ __forceinline__ void xcd_swizzle(int& bx, int& by) {
  const int gx = gridDim.x;
  const int nwg = gx * gridDim.y;
  if ((nwg & 7) == 0) {
    int id = by * gx + bx;
    const int per = nwg >> 3;
    id = (id & 7) * per + (id >> 3);
    bx = id % gx;
    by = id / gx;
  }
}

// ============================================================================
// 256x256 8-phase GEMM (T2+T3+T4+T5): C[i,j] = sum_d A[i,d]*B[j,d] (+bias[j])
// MODE 0: fp32 store; 1: bf16 store (+bias); 2: bf16 relu store (+bias)
// Fragment reads deduped: 24 ds_read_b128/wave/K-tile (12/4/8/0 per phase).
// LDS: 2 buf x {A0,A1,B0,B1} halves of 128x64. Swizzle: 16B slot ^= (row&7).
// ============================================================================
template <int MODE>
__global__ __launch_bounds__(512) void gemm256(
    const bf16_t* __restrict__ Aop, int lda,
    const bf16_t* __restrict__ Bop, int ldb,
    void* __restrict__ Cp, int ldc,
    const float* __restrict__ bias, int Kd) {
  __shared__ __attribute__((aligned(16))) bf16_t LDS[2][4][128][64];
  const int t = threadIdx.x;
  const int l = t & 63;
  const int w = t >> 6;   // 0..7
  const int qr = w >> 2;  // 0..1: row-half within quadrant
  const int qc = w & 3;   // 0..3: col-quarter within quadrant
  int bxs = blockIdx.x, bys = blockIdx.y;
  xcd_swizzle(bxs, bys);
  const int brow = bys * 256;
  const int bcol = bxs * 256;

  const int sr = t >> 3;  // 0..63
  const int sl8 = (((t & 7) ^ (sr & 7)) * 8);
  const int sp8 = (t & 7) * 8;

  f32x4 acc[2][2][4][2] = {};  // [mh][nh][m][n]
  bf16x8 afr[4][2];            // current A-half fragments
  bf16x8 bfr[2][2][2];         // [half][n][ks] — both B-halves live

  auto STAGE = [&](int tile, int reg) {
    const int bufS = tile & 1;
    const bf16_t* src;
    size_t ld;
    int grow;
    if (reg < 2) {
      src = Aop; ld = (size_t)lda; grow = brow + reg * 128;
    } else {
      src = Bop; ld = (size_t)ldb; grow = bcol + (reg - 2) * 128;
    }
    const bf16_t* g0 = src + (size_t)(grow + sr) * ld + tile * 64 + sl8;
    bf16_t* d0 = &LDS[bufS][reg][sr][sp8];
    gld_lds16(g0, d0);
    gld_lds16(g0 + 64 * ld, d0 + 64 * 64);
  };

#define READ_A(buf, half)                                          \
  _Pragma("unroll") for (int m = 0; m < 4; ++m) {                  \
    const int r = qr * 64 + m * 16 + (l & 15);                     \
    _Pragma("unroll") for (int ks = 0; ks < 2; ++ks) {             \
      const int s = (((ks * 4 + (l >> 4)) ^ (r & 7)) * 8);         \
      afr[m][ks] = *(const bf16x8*)&LDS[buf][half][r][s];          \
    }                                                              \
  }
#define READ_B(buf, half)                                          \
  _Pragma("unroll") for (int n = 0; n < 2; ++n) {                  \
    const int c = qc * 32 + n * 16 + (l & 15);                     \
    _Pragma("unroll") for (int ks = 0; ks < 2; ++ks) {             \
      const int s = (((ks * 4 + (l >> 4)) ^ (c & 7)) * 8);         \
      bfr[half][n][ks] = *(const bf16x8*)&LDS[buf][2 + half][c][s];\
    }                                                              \
  }
#define MFMA_Q(MH, NH, BH)                                                  \
  __builtin_amdgcn_s_setprio(1);                                            \
  _Pragma("unroll") for (int m = 0; m < 4; ++m)                             \
      _Pragma("unroll") for (int n = 0; n < 2; ++n)                         \
          _Pragma("unroll") for (int ks = 0; ks < 2; ++ks)                  \
              acc[MH][NH][m][n] = __builtin_amdgcn_mfma_f32_16x16x32_bf16(  \
                  afr[m][ks], bfr[BH][n][ks], acc[MH][NH][m][n], 0, 0, 0);  \
  __builtin_amdgcn_s_setprio(0);

  const int NT = Kd >> 6;
  STAGE(0, 0); STAGE(0, 1); STAGE(0, 2); STAGE(0, 3);
  STAGE(1, 0); STAGE(1, 2);
  VMCNT(4);
  barrier_raw();

  for (int tt = 0; tt < NT; ++tt) {
    const int buf = tt & 1;
    const bool s1 = (tt + 1 < NT);
    const bool s2 = (tt + 2 < NT);

    READ_A(buf, 0);
    READ_B(buf, 0);
    if (s1) STAGE(tt + 1, 1);
    LGKMCNT(8);
    barrier_raw();
    LGKMCNT(0);
    MFMA_Q(0, 0, 0);
    barrier_raw();

    READ_B(buf, 1);
    if (s1) STAGE(tt + 1, 3);
    barrier_raw();
    LGKMCNT(0);
    MFMA_Q(0, 1, 1);
    barrier_raw();

    READ_A(buf, 1);
    if (s2) STAGE(tt + 2, 0);
    barrier_raw();
    LGKMCNT(0);
    MFMA_Q(1, 0, 0);
    barrier_raw();

    if (s2) STAGE(tt + 2, 2);
    barrier_raw();
    MFMA_Q(1, 1, 1);
    if (tt < NT - 2) { VMCNT(4); } else { VMCNT(0); }
    barrier_raw();
  }
#undef READ_A
#undef READ_B
#undef MFMA_Q

#pragma unroll
  for (int mh = 0; mh < 2; ++mh)
#pragma unroll
    for (int nh = 0; nh < 2; ++nh)
#pragma unroll
      for (int m = 0; m < 4; ++m)
#pragma unroll
        for (int n = 0; n < 2; ++n) {
          const int col = bcol + nh * 128 + qc * 32 + n * 16 + (l & 15);
          const int row0 = brow + mh * 128 + qr * 64 + m * 16 + (l >> 4) * 4;
          const float bv = bias ? bias[col] : 0.0f;
#pragma unroll
          for (int r = 0; r < 4; ++r) {
            const float v = acc[mh][nh][m][n][r] + bv;
            const size_t idx = (size_t)(row0 + r) * ldc + col;
            if (MODE == 0)
              ((float*)Cp)[idx] = v;
            else if (MODE == 1)
              ((bf16_t*)Cp)[idx] = (bf16_t)v;
            else
              ((bf16_t*)Cp)[idx] = (bf16_t)fmaxf(v, 0.0f);
          }
        }
}

// ============================================================================
// 128xBN m97-structure GEMM. Supports split-K via blockIdx.z:
// A,B advanced by z*Kd along k; MODE 0 output advanced by z*zstride floats.
// MODE 0: fp32 store (partial); 1: bf16 store; 4: fp32 Cp += v, Cb = bf16(new)
// ============================================================================
template <int MODE, int BN>
__global__ __launch_bounds__(256) void gemm_nt(
    const bf16_t* __restrict__ A, int lda,
    const bf16_t* __restrict__ B, int ldb,
    void* __restrict__ Cp, int ldc,
    const float* __restrict__ bias,
    int Kd, bf16_t* __restrict__ Cb, size_t zstride) {
  __shared__ __attribute__((aligned(16))) bf16_t As[128 * 32];
  __shared__ __attribute__((aligned(16))) bf16_t Bs[BN * 32];
  const int t = threadIdx.x;
  const int l = t & 63;
  const int w = t >> 6;
  int bxs = blockIdx.x, bys = blockIdx.y;
  xcd_swizzle(bxs, bys);
  const int brow = bys * 128;
  const int bcol = bxs * BN;
  const int wr = (w >> 1) * 64;
  const int wc = (w & 1) * (BN / 2);
  constexpr int NF = BN / 32;

  const int z = blockIdx.z;
  A += (size_t)z * Kd;
  B += (size_t)z * Kd;
  float* Cpf = (float*)Cp + (size_t)z * zstride;

  f32x4 acc[4][NF] = {};

  const int srow = t >> 2;
  const int scol = (t & 3) * 8;
  const bf16_t* Ag = A + (size_t)(brow + srow) * lda + scol;
  const bf16_t* Bg = B + (size_t)(bcol + srow) * ldb + scol;
  bf16_t* AsD = &As[t * 8];
  bf16_t* BsD = &Bs[t * 8];

  const int arow = wr + (l & 15);
  const int brw = wc + (l & 15);
  const int kq = (l >> 4) * 8;

  for (int kt = 0; kt < Kd; kt += 32) {
    if (kt) __syncthreads();
    gld_lds16(Ag + kt, AsD);
    gld_lds16(Ag + kt + (size_t)64 * lda, AsD + 2048);
    gld_lds16(Bg + kt, BsD);
    if (BN == 128) gld_lds16(Bg + kt + (size_t)64 * ldb, BsD + 2048);
    __syncthreads();
    bf16x8 af[4], bfr[NF];
#pragma unroll
    for (int mi = 0; mi < 4; ++mi)
      af[mi] = *(const bf16x8*)&As[(arow + mi * 16) * 32 + kq];
#pragma unroll
    for (int ni = 0; ni < NF; ++ni)
      bfr[ni] = *(const bf16x8*)&Bs[(brw + ni * 16) * 32 + kq];
#pragma unroll
    for (int mi = 0; mi < 4; ++mi)
#pragma unroll
      for (int ni = 0; ni < NF; ++ni)
        acc[mi][ni] = __builtin_amdgcn_mfma_f32_16x16x32_bf16(
            af[mi], bfr[ni], acc[mi][ni], 0, 0, 0);
  }

  const int crow0 = brow + wr + (l >> 4) * 4;
  const int ccol0 = bcol + wc + (l & 15);
#pragma unroll
  for (int mi = 0; mi < 4; ++mi) {
#pragma unroll
    for (int ni = 0; ni < NF; ++ni) {
      const int col = ccol0 + ni * 16;
      const float bv = (MODE == 4 && bias) ? bias[col] : 0.0f;
#pragma unroll
      for (int r = 0; r < 4; ++r) {
        const int row = crow0 + mi * 16 + r;
        const float v = acc[mi][ni][r] + bv;
        const size_t idx = (size_t)row * ldc + col;
        if (MODE == 0) {
          Cpf[idx] = v;
        } else if (MODE == 1) {
          ((bf16_t*)Cp)[idx] = (bf16_t)v;
        } else {
          const float nv = ((float*)Cp)[idx] + v;
          ((float*)Cp)[idx] = nv;
          Cb[idx] = (bf16_t)nv;
        }
      }
    }
  }
}

// o = bf16(p0 + p1)  over n4*4 fp32 elements (two 16MB partials)
__global__ __launch_bounds__(256) void combine_pv(
    const float* __restrict__ p, bf16_t* __restrict__ o, int n4) {
  const int stride = gridDim.x * 256;
  const float4* p0 = (const float4*)p;
  const float4* p1 = (const float4*)(p + (size_t)SEQ * KEY);
  for (int i = blockIdx.x * 256 + threadIdx.x; i < n4; i += stride) {
    const float4 a = p0[i];
    const float4 b = p1[i];
    bf16x4 v;
    v[0] = (bf16_t)(a.x + b.x);
    v[1] = (bf16_t)(a.y + b.y);
    v[2] = (bf16_t)(a.z + b.z);
    v[3] = (bf16_t)(a.w + b.w);
    ((bf16x4*)o)[i] = v;
  }
}

// h += p0 + p1 + bias[col]; hb = bf16(h)   (ldc == DIM)
__global__ __launch_bounds__(256) void combine_res(
    const float* __restrict__ p, const float* __restrict__ bias,
    float* __restrict__ h, bf16_t* __restrict__ hb, int n4) {
  const int stride = gridDim.x * 256;
  const float4* p0 = (const float4*)p;
  const float4* p1 = (const float4*)(p + (size_t)SEQ * DIM);
  for (int i = blockIdx.x * 256 + threadIdx.x; i < n4; i += stride) {
    const float4 a = p0[i];
    const float4 b = p1[i];
    const float4 bv = ((const float4*)bias)[i & (DIM / 4 - 1)];
    float4 hv = ((float4*)h)[i];
    hv.x += a.x + b.x + bv.x;
    hv.y += a.y + b.y + bv.y;
    hv.z += a.z + b.z + bv.z;
    hv.w += a.w + b.w + bv.w;
    ((float4*)h)[i] = hv;
    bf16x4 v;
    v[0] = (bf16_t)hv.x;
    v[1] = (bf16_t)hv.y;
    v[2] = (bf16_t)hv.z;
    v[3] = (bf16_t)hv.w;
    ((bf16x4*)hb)[i] = v;
  }
}

// row-wise softmax over 4096 bf16 -> bf16
__global__ __launch_bounds__(256) void softmax_kernel(
    const bf16_t* __restrict__ S, bf16_t* __restrict__ P) {
  const int row = blockIdx.x;
  const int t = threadIdx.x;
  const bf16x8* s8 = (const bf16x8*)(S + (size_t)row * SEQ);
  float v[16];
  float mx = -3.0e38f;
#pragma unroll
  for (int j = 0; j < 2; ++j) {
    const bf16x8 raw = s8[j * 256 + t];
#pragma unroll
    for (int e = 0; e < 8; ++e) {
      v[j * 8 + e] = (float)raw[e];
      mx = fmaxf(mx, v[j * 8 + e]);
    }
  }
#pragma unroll
  for (int off = 32; off >= 1; off >>= 1) mx = fmaxf(mx, __shfl_xor(mx, off));
  __shared__ float redm[4];
  __shared__ float reds[4];
  if ((t & 63) == 0) redm[t >> 6] = mx;
  __syncthreads();
  mx = fmaxf(fmaxf(redm[0], redm[1]), fmaxf(redm[2], redm[3]));
  float sum = 0.0f;
#pragma unroll
  for (int e = 0; e < 16; ++e) {
    v[e] = __expf(v[e] - mx);
    sum += v[e];
  }
#pragma unroll
  for (int off = 32; off >= 1; off >>= 1) sum += __shfl_xor(sum, off);
  if ((t & 63) == 0) reds[t >> 6] = sum;
  __syncthreads();
  sum = reds[0] + reds[1] + reds[2] + reds[3];
  const float inv = 1.0f / sum;
  bf16x8* p8 = (bf16x8*)(P + (size_t)row * SEQ);
#pragma unroll
  for (int j = 0; j < 2; ++j) {
    bf16x8 o;
#pragma unroll
    for (int e = 0; e < 8; ++e) o[e] = (bf16_t)(v[j * 8 + e] * inv);
    p8[j * 256 + t] = o;
  }
}

// fp32 [R][C] -> bf16 [C][R]
__global__ void cvtT_kernel(const float* __restrict__ in,
                            bf16_t* __restrict__ out, int R, int C) {
  __shared__ float tile[32][33];
  const int c0 = blockIdx.x * 32, r0 = blockIdx.y * 32;
  const int x = threadIdx.x, y = threadIdx.y;
#pragma unroll
  for (int k = 0; k < 4; ++k)
    tile[y + 8 * k][x] = in[(size_t)(r0 + y + 8 * k) * C + c0 + x];
  __syncthreads();
#pragma unroll
  for (int k = 0; k < 4; ++k)
    out[(size_t)(c0 + y + 8 * k) * R + r0 + x] = (bf16_t)tile[x][y + 8 * k];
}

// batched: z selects Wq/Wk/Wv [D][K]; out rows z*K + [0,K)
__global__ void cvtT_qkv(const float* __restrict__ Wq,
                         const float* __restrict__ Wk,
                         const float* __restrict__ Wv,
                         bf16_t* __restrict__ out) {
  __shared__ float tile[32][33];
  const int z = blockIdx.z;
  const float* in = (z == 0) ? Wq : (z == 1) ? Wk : Wv;
  bf16_t* o = out + (size_t)z * KEY * DIM;
  const int c0 = blockIdx.x * 32, r0 = blockIdx.y * 32;
  const int x = threadIdx.x, y = threadIdx.y;
#pragma unroll
  for (int k = 0; k < 4; ++k)
    tile[y + 8 * k][x] = in[(size_t)(r0 + y + 8 * k) * KEY + c0 + x];
  __syncthreads();
#pragma unroll
  for (int k = 0; k < 4; ++k)
    o[(size_t)(c0 + y + 8 * k) * DIM + r0 + x] = (bf16_t)tile[x][y + 8 * k];
}

__global__ void bias_cat3(const float* __restrict__ a,
                          const float* __restrict__ b,
                          const float* __restrict__ c,
                          float* __restrict__ out) {
  const int i = blockIdx.x * 256 + threadIdx.x;
  if (i < KEY)
    out[i] = a[i];
  else if (i < 2 * KEY)
    out[i] = b[i - KEY];
  else if (i < 3 * KEY)
    out[i] = c[i - 2 * KEY];
}

// bf16 [R][C] (ldin) -> bf16 [C][R]
__global__ void transT_bf16(const bf16_t* __restrict__ in, int ldin,
                            bf16_t* __restrict__ out, int R, int C) {
  __shared__ bf16_t tile[32][33];
  const int c0 = blockIdx.x * 32, r0 = blockIdx.y * 32;
  const int x = threadIdx.x, y = threadIdx.y;
#pragma unroll
  for (int k = 0; k < 4; ++k)
    tile[y + 8 * k][x] = in[(size_t)(r0 + y + 8 * k) * ldin + c0 + x];
  __syncthreads();
#pragma unroll
  for (int k = 0; k < 4; ++k)
    out[(size_t)(c0 + y + 8 * k) * R + r0 + x] = tile[x][y + 8 * k];
}

__global__ __launch_bounds__(256) void embed_kernel(
    const int* __restrict__ x, const float* __restrict__ tok,
    const float* __restrict__ pos, float* __restrict__ h,
    bf16_t* __restrict__ hb) {
  const int n = blockIdx.x, t = threadIdx.x;
  const int id = x[n];
  const float4 a = ((const float4*)(tok + (size_t)id * DIM))[t];
  const float4 b = ((const float4*)(pos + (size_t)n * DIM))[t];
  float4 o;
  o.x = a.x + b.x;
  o.y = a.y + b.y;
  o.z = a.z + b.z;
  o.w = a.w + b.w;
  ((float4*)(h + (size_t)n * DIM))[t] = o;
  bf16x4 ob;
  ob[0] = (bf16_t)o.x;
  ob[1] = (bf16_t)o.y;
  ob[2] = (bf16_t)o.z;
  ob[3] = (bf16_t)o.w;
  ((bf16x4*)(hb + (size_t)n * DIM))[t] = ob;
}

// out[n,v] = v < DIM ? h[n,v] : 0
__global__ __launch_bounds__(256) void output_kernel(
    const float* __restrict__ h, float* __restrict__ out) {
  const int n = blockIdx.y;
  const int i4 = blockIdx.x * 256 + threadIdx.x;
  if (i4 >= VOC / 4) return;
  float4 v = make_float4(0.0f, 0.0f, 0.0f, 0.0f);
  if (i4 < DIM / 4) v = ((const float4*)(h + (size_t)n * DIM))[i4];
  ((float4*)(out + (size_t)n * VOC))[i4] = v;
}

extern "C" void kernel_launch(void* const* d_in, const int* in_sizes, int n_in,
                              void* d_out, int out_size, void* d_ws,
                              size_t ws_size, hipStream_t stream) {
  const int* x = (const int*)d_in[0];
  const float* tok = (const float*)d_in[1];
  const float* pos = (const float*)d_in[2];
  const float* Wq = (const float*)d_in[3];
  const float* bq = (const float*)d_in[4];
  const float* Wk = (const float*)d_in[5];
  const float* bk = (const float*)d_in[6];
  const float* Wv = (const float*)d_in[7];
  const float* bv = (const float*)d_in[8];
  const float* Wo = (const float*)d_in[9];
  const float* bo = (const float*)d_in[10];
  const float* W1 = (const float*)d_in[11];
  const float* b1 = (const float*)d_in[12];
  const float* W2 = (const float*)d_in[13];
  const float* b2 = (const float*)d_in[14];
  float* out = (float*)d_out;

  char* ws = (char*)d_ws;
  constexpr size_t MB = 1ull << 20;
  float* h = (float*)(ws + 0);              // 16MB fp32 residual
  bf16_t* hb = (bf16_t*)(ws + 16 * MB);     // 8MB bf16 mirror of h
  bf16_t* qkv = (bf16_t*)(ws + 24 * MB);    // 24MB  [4096][3072]
  bf16_t* vT = (bf16_t*)(ws + 48 * MB);     // 8MB   [1024][4096]
  bf16_t* Ob = (bf16_t*)(ws + 56 * MB);     // 8MB   [4096][1024]
  bf16_t* Sb = (bf16_t*)(ws + 64 * MB);     // 32MB  [4096][4096] bf16 logits
  bf16_t* mh = (bf16_t*)(ws + 64 * MB);     // 32MB (aliases Sb; disjoint)
  float* parts = (float*)(ws + 96 * MB);    // 32MB  2 x [4096][1024] fp32
  bf16_t* P = (bf16_t*)(ws + 128 * MB);     // 32MB  [4096][4096]
  bf16_t* WqkvT = (bf16_t*)(ws + 160 * MB); // 6MB   [3072][1024]
  bf16_t* WoT = (bf16_t*)(ws + 166 * MB);   // 2MB
  bf16_t* W1T = (bf16_t*)(ws + 168 * MB);   // 8MB
  bf16_t* W2T = (bf16_t*)(ws + 176 * MB);   // 8MB
  float* bqkv = (float*)(ws + 184 * MB);    // 12KB

  embed_kernel<<<SEQ, 256, 0, stream>>>(x, tok, pos, h, hb);

  const dim3 tb(32, 8);
  for (int l = 0; l < NLAYER; ++l) {
    const float* lWq = Wq + (size_t)l * DIM * KEY;
    const float* lWk = Wk + (size_t)l * DIM * KEY;
    const float* lWv = Wv + (size_t)l * DIM * KEY;
    const float* lWo = Wo + (size_t)l * KEY * DIM;
    const float* lW1 = W1 + (size_t)l * DIM * MLP;
    const float* lW2 = W2 + (size_t)l * MLP * DIM;

    cvtT_qkv<<<dim3(KEY / 32, DIM / 32, 3), tb, 0, stream>>>(lWq, lWk, lWv, WqkvT);
    bias_cat3<<<12, 256, 0, stream>>>(bq + (size_t)l * KEY, bk + (size_t)l * KEY,
                                      bv + (size_t)l * KEY, bqkv);
    cvtT_kernel<<<dim3(DIM / 32, KEY / 32), tb, 0, stream>>>(lWo, WoT, KEY, DIM);
    cvtT_kernel<<<dim3(MLP / 32, DIM / 32), tb, 0, stream>>>(lW1, W1T, DIM, MLP);
    cvtT_kernel<<<dim3(DIM / 32, MLP / 32), tb, 0, stream>>>(lW2, W2T, MLP, DIM);

    // qkv = hb @ Wqkv^T + bqkv   [4096][3072]  (8-phase 256^2)
    gemm256<1><<<dim3(3 * KEY / 256, SEQ / 256), 512, 0, stream>>>(
        hb, DIM, WqkvT, DIM, qkv, 3 * KEY, bqkv, DIM);

    const bf16_t* qb = qkv;
    const bf16_t* kb = qkv + KEY;
    const bf16_t* vb = qkv + 2 * KEY;

    transT_bf16<<<dim3(KEY / 32, SEQ / 32), tb, 0, stream>>>(vb, 3 * KEY, vT, SEQ, KEY);

    // Sb = Q K^T  [4096 x 4096] bf16  (8-phase 256^2)
    gemm256<1><<<dim3(SEQ / 256, SEQ / 256), 512, 0, stream>>>(
        qb, 3 * KEY, kb, 3 * KEY, Sb, SEQ, nullptr, KEY);

    softmax_kernel<<<SEQ, 256, 0, stream>>>(Sb, P);

    // O = P V  via split-K=2: partials fp32, then combine -> Ob bf16
    gemm_nt<0, 128><<<dim3(KEY / 128, SEQ / 128, 2), 256, 0, stream>>>(
        P, SEQ, vT, SEQ, parts, KEY, nullptr, SEQ / 2, nullptr,
        (size_t)SEQ * KEY);
    combine_pv<<<2048, 256, 0, stream>>>(parts, Ob, SEQ * KEY / 4);

    // h += O Wo + bo ; hb = bf16(h)
    gemm_nt<4, 64><<<dim3(DIM / 64, SEQ / 128), 256, 0, stream>>>(
        Ob, KEY, WoT, KEY, h, DIM, bo + (size_t)l * DIM, KEY, hb, 0);

    // mh = relu(hb W1 + b1)   (8-phase 256^2)
    gemm256<2><<<dim3(MLP / 256, SEQ / 256), 512, 0, stream>>>(
        hb, DIM, W1T, DIM, mh, MLP, b1 + (size_t)l * MLP, DIM);

    // h += mh W2 + b2 via split-K=2 partials + combine (residual+bias+mirror)
    gemm_nt<0, 128><<<dim3(DIM / 128, SEQ / 128, 2), 256, 0, stream>>>(
        mh, MLP, W2T, MLP, parts, DIM, nullptr, MLP / 2, nullptr,
        (size_t)SEQ * DIM);
    combine_res<<<2048, 256, 0, stream>>>(parts, b2 + (size_t)l * DIM, h, hb,
                                          SEQ * DIM / 4);
  }

  output_kernel<<<dim3((VOC / 4 + 255) / 256, SEQ), 256, 0, stream>>>(h, out);
}